// Round 1
// baseline (4400.108 us; speedup 1.0000x reference)
//
#include <hip/hip_runtime.h>

// ---------------------------------------------------------------------------
// Problem constants
// ---------------------------------------------------------------------------
#define V_PREV 16384
#define V_NEXT 65536
#define F_IN   512
#define F_OUT  256
#define NNZ_UP 65536
#define N_EDGE 524288

using f32x4 = __attribute__((ext_vector_type(4))) float;
using bfrag = __attribute__((ext_vector_type(8))) short;   // 8 x bf16

__device__ __forceinline__ ushort f2bf(float f) {
    union { float f; unsigned u; } v; v.f = f;
    unsigned r = (v.u + 0x7FFFu + ((v.u >> 16) & 1u)) >> 16;
    return (ushort)r;
}
__device__ __forceinline__ float bf2f(ushort h) {
    union { unsigned u; float f; } v; v.u = ((unsigned)h) << 16; return v.f;
}

// ---------------------------------------------------------------------------
// Weight prep: transpose + convert to bf16, build concatenated weight mats
//   WresT [256][512]  (n,k)  = W_res[k][n]
//   W0t   [512][512]  (n,k)  = n<256 ? Uj0_W[k][n] : Ui0_W[k][n-256]
//   W1t   [512][256]  (n,k)  = n<256 ? Uj1_W[k][n] : Ui1_W[k][n-256]
//   bias1 [512]              = [Uj1_b | Ui1_b]
// ---------------------------------------------------------------------------
__global__ void prep_weights_kernel(const float* __restrict__ Wres,
                                    const float* __restrict__ Ui0W, const float* __restrict__ Uj0W,
                                    const float* __restrict__ Ui1W, const float* __restrict__ Uj1W,
                                    const float* __restrict__ Ui1b, const float* __restrict__ Uj1b,
                                    ushort* __restrict__ WresT, ushort* __restrict__ W0t,
                                    ushort* __restrict__ W1t, float* __restrict__ bias1)
{
    int i = blockIdx.x * blockDim.x + threadIdx.x;   // 0 .. 512*512-1
    if (i < 256 * 512) {
        int n = i / 512, k = i % 512;
        WresT[i] = f2bf(Wres[k * 256 + n]);
    }
    if (i < 512 * 512) {
        int n = i / 512, k = i % 512;
        W0t[i] = f2bf(n < 256 ? Uj0W[k * 256 + n] : Ui0W[k * 256 + (n - 256)]);
    }
    if (i < 512 * 256) {
        int n = i / 256, k = i % 256;
        W1t[i] = f2bf(n < 256 ? Uj1W[k * 256 + n] : Ui1W[k * 256 + (n - 256)]);
    }
    if (i < 512) bias1[i] = (i < 256) ? Uj1b[i] : Ui1b[i - 256];
}

// ---------------------------------------------------------------------------
// BatchNorm stats, stage 1: per-block partial sums.  x [16384,512]
// grid 64 blocks x 256 thr; block handles 256 rows; thread handles ch t,t+256
// ---------------------------------------------------------------------------
__global__ void bn0_part_kernel(const float* __restrict__ x,
                                float* __restrict__ psum, float* __restrict__ psq)
{
    int blk = blockIdx.x, t = threadIdx.x;
    float s0 = 0, s1 = 0, q0 = 0, q1 = 0;
    for (int r = 0; r < 256; r++) {
        size_t base = ((size_t)blk * 256 + r) * 512;
        float a = x[base + t], b = x[base + t + 256];
        s0 += a; q0 += a * a; s1 += b; q1 += b * b;
    }
    psum[blk * 512 + t] = s0; psum[blk * 512 + t + 256] = s1;
    psq [blk * 512 + t] = q0; psq [blk * 512 + t + 256] = q1;
}

// x2 [65536,256]; grid 256 blocks x 256 thr; block handles 256 rows
__global__ void bn1_part_kernel(const float* __restrict__ xx,
                                float* __restrict__ psum, float* __restrict__ psq)
{
    int blk = blockIdx.x, t = threadIdx.x;
    float s = 0, q = 0;
    for (int r = 0; r < 256; r++) {
        float a = xx[((size_t)blk * 256 + r) * 256 + t];
        s += a; q += a * a;
    }
    psum[blk * 256 + t] = s; psq[blk * 256 + t] = q;
}

__global__ void bn_finish_kernel(const float* __restrict__ psum, const float* __restrict__ psq,
                                 int nblocks, int C, float invN,
                                 float* __restrict__ mean, float* __restrict__ rstd)
{
    int c = blockIdx.x * blockDim.x + threadIdx.x;
    if (c >= C) return;
    float s = 0, q = 0;
    for (int i = 0; i < nblocks; i++) { s += psum[i * C + c]; q += psq[i * C + c]; }
    float m = s * invN;
    float v = q * invN - m * m;
    mean[c] = m;
    rstd[c] = rsqrtf(v + 1e-5f);
}

// ---------------------------------------------------------------------------
// bn0 apply: xb = bf16(x), xnb = bf16(relu(bn0(x)))   over [16384,512]
// ---------------------------------------------------------------------------
__global__ void bn0_apply_kernel(const float* __restrict__ x,
                                 const float* __restrict__ mean, const float* __restrict__ rstd,
                                 const float* __restrict__ g, const float* __restrict__ b,
                                 ushort* __restrict__ xb, ushort* __restrict__ xnb)
{
    size_t i4 = ((size_t)blockIdx.x * blockDim.x + threadIdx.x) * 4;
    if (i4 >= (size_t)V_PREV * F_IN) return;
    float4 v = *(const float4*)&x[i4];
    int c = (int)(i4 & 511);
    float vv[4] = { v.x, v.y, v.z, v.w };
    ushort xs[4], ns[4];
#pragma unroll
    for (int j = 0; j < 4; j++) {
        int cc = c + j;
        float t = (vv[j] - mean[cc]) * rstd[cc] * g[cc] + b[cc];
        t = fmaxf(t, 0.0f);
        xs[j] = f2bf(vv[j]);
        ns[j] = f2bf(t);
    }
    *(ushort4*)&xb[i4]  = make_ushort4(xs[0], xs[1], xs[2], xs[3]);
    *(ushort4*)&xnb[i4] = make_ushort4(ns[0], ns[1], ns[2], ns[3]);
}

// bn1 apply: h1 = bf16(relu(bn1(xx)))  over [65536,256]
__global__ void bn1_apply_kernel(const float* __restrict__ xx,
                                 const float* __restrict__ mean, const float* __restrict__ rstd,
                                 const float* __restrict__ g, const float* __restrict__ b,
                                 ushort* __restrict__ h1)
{
    size_t i4 = ((size_t)blockIdx.x * blockDim.x + threadIdx.x) * 4;
    if (i4 >= (size_t)V_NEXT * F_OUT) return;
    float4 v = *(const float4*)&xx[i4];
    int c = (int)(i4 & 255);
    float vv[4] = { v.x, v.y, v.z, v.w };
    ushort ns[4];
#pragma unroll
    for (int j = 0; j < 4; j++) {
        int cc = c + j;
        float t = (vv[j] - mean[cc]) * rstd[cc] * g[cc] + b[cc];
        ns[j] = f2bf(fmaxf(t, 0.0f));
    }
    *(ushort4*)&h1[i4] = make_ushort4(ns[0], ns[1], ns[2], ns[3]);
}

// ---------------------------------------------------------------------------
// bf16 GEMM: C[M,N] (bf16) = A[M,K] (bf16) @ Bt[N,K]^T (bf16)  (+ bias[N])
// 128x128 tile, BK=32, 4 waves (2x2), each wave 64x64, mfma 16x16x32.
// M,N multiples of 128; K multiple of 32.
// ---------------------------------------------------------------------------
__global__ __launch_bounds__(256)
void gemm_bf16_kernel(const ushort* __restrict__ A, const ushort* __restrict__ Bt,
                      ushort* __restrict__ C, const float* __restrict__ bias,
                      int M, int N, int K)
{
    __shared__ ushort As[128 * 40];   // padded stride 40 shorts = 80B (16B aligned)
    __shared__ ushort Bs[128 * 40];

    const int tid  = threadIdx.x;
    const int lane = tid & 63;
    const int wave = tid >> 6;
    const int wm = wave >> 1, wn = wave & 1;
    const int lr = lane & 15, lg = lane >> 4;
    const int tM = blockIdx.y * 128, tN = blockIdx.x * 128;

    const int r0 = tid >> 2;            // 0..63
    const int s0 = (tid & 3) * 8;       // 0,8,16,24

    f32x4 acc[4][4] = {};

    for (int k0 = 0; k0 < K; k0 += 32) {
        // stage A tile (128 x 32) and B tile (128 n-rows x 32 k)
        *(uint4*)&As[(r0     ) * 40 + s0] = *(const uint4*)&A[(size_t)(tM + r0     ) * K + k0 + s0];
        *(uint4*)&As[(r0 + 64) * 40 + s0] = *(const uint4*)&A[(size_t)(tM + r0 + 64) * K + k0 + s0];
        *(uint4*)&Bs[(r0     ) * 40 + s0] = *(const uint4*)&Bt[(size_t)(tN + r0     ) * K + k0 + s0];
        *(uint4*)&Bs[(r0 + 64) * 40 + s0] = *(const uint4*)&Bt[(size_t)(tN + r0 + 64) * K + k0 + s0];
        __syncthreads();

        bfrag af[4], bfv[4];
#pragma unroll
        for (int mm = 0; mm < 4; mm++)
            af[mm] = *(const bfrag*)&As[(wm * 64 + mm * 16 + lr) * 40 + lg * 8];
#pragma unroll
        for (int nn = 0; nn < 4; nn++)
            bfv[nn] = *(const bfrag*)&Bs[(wn * 64 + nn * 16 + lr) * 40 + lg * 8];
#pragma unroll
        for (int mm = 0; mm < 4; mm++)
#pragma unroll
            for (int nn = 0; nn < 4; nn++)
                acc[mm][nn] = __builtin_amdgcn_mfma_f32_16x16x32_bf16(af[mm], bfv[nn], acc[mm][nn], 0, 0, 0);
        __syncthreads();
    }

    // epilogue: D row = 4*lg + reg, col = lr (within each 16x16)
#pragma unroll
    for (int mm = 0; mm < 4; mm++) {
#pragma unroll
        for (int nn = 0; nn < 4; nn++) {
#pragma unroll
            for (int r = 0; r < 4; r++) {
                int row = tM + wm * 64 + mm * 16 + lg * 4 + r;
                int col = tN + wn * 64 + nn * 16 + lr;
                float v = acc[mm][nn][r];
                if (bias) v += bias[col];
                C[(size_t)row * N + col] = f2bf(v);
            }
        }
    }
}

// ---------------------------------------------------------------------------
// Init V_NEXT-sized accumulator buffers with their per-channel biases
// ---------------------------------------------------------------------------
__global__ void init_upbufs_kernel(float* __restrict__ R, float* __restrict__ UJ, float* __restrict__ UI,
                                   const float* __restrict__ b_res,
                                   const float* __restrict__ uj_b, const float* __restrict__ ui_b)
{
    size_t i4 = ((size_t)blockIdx.x * blockDim.x + threadIdx.x) * 4;
    if (i4 >= (size_t)V_NEXT * F_OUT) return;
    int f = (int)(i4 & 255);
    float4 r = make_float4(b_res[f], b_res[f + 1], b_res[f + 2], b_res[f + 3]);
    float4 j = make_float4(uj_b[f],  uj_b[f + 1],  uj_b[f + 2],  uj_b[f + 3]);
    float4 u = make_float4(ui_b[f],  ui_b[f + 1],  ui_b[f + 2],  ui_b[f + 3]);
    *(float4*)&R [i4] = r;
    *(float4*)&UJ[i4] = j;
    *(float4*)&UI[i4] = u;
}

// ---------------------------------------------------------------------------
// Upsample scatter: for nnz k (row r, col c, val s):
//   R [r] += s * XW [c]          (residual path, raw x @ W_res)
//   UJ[r] += s * XNU[c, 0:256]   (xn @ Uj0_W)
//   UI[r] += s * XNU[c, 256:512] (xn @ Ui0_W)
// 4 nnz per block, 64 lanes per nnz, 4 channels per lane.
// ---------------------------------------------------------------------------
__global__ __launch_bounds__(256)
void up_scatter_kernel(const int* __restrict__ up_row, const int* __restrict__ up_col,
                       const float* __restrict__ up_val,
                       const ushort* __restrict__ XNU, const ushort* __restrict__ XW,
                       float* __restrict__ R, float* __restrict__ UJ, float* __restrict__ UI)
{
    int g = threadIdx.x >> 6, lane = threadIdx.x & 63;
    int k = blockIdx.x * 4 + g;
    int r = up_row[k], c = up_col[k];
    float s = up_val[k];
    int f = lane * 4;
    ushort4 uj = *(const ushort4*)&XNU[(size_t)c * 512 + f];
    ushort4 ui = *(const ushort4*)&XNU[(size_t)c * 512 + 256 + f];
    ushort4 xw = *(const ushort4*)&XW[(size_t)c * 256 + f];
    const ushort* ujp = (const ushort*)&uj;
    const ushort* uip = (const ushort*)&ui;
    const ushort* xwp = (const ushort*)&xw;
#pragma unroll
    for (int jj = 0; jj < 4; jj++) {
        atomicAdd(&UJ[(size_t)r * 256 + f + jj], s * bf2f(ujp[jj]));
        atomicAdd(&UI[(size_t)r * 256 + f + jj], s * bf2f(uip[jj]));
        atomicAdd(&R [(size_t)r * 256 + f + jj], s * bf2f(xwp[jj]));
    }
}

// ---------------------------------------------------------------------------
// Edge scatter (layer 0): O[dst] += w * T[src], T fp32 [65536,256]
// ---------------------------------------------------------------------------
__global__ __launch_bounds__(256)
void edge_scatter_f32_kernel(const int* __restrict__ src, const int* __restrict__ dst,
                             const float* __restrict__ adjv,
                             const float* __restrict__ T, float* __restrict__ O)
{
    int g = threadIdx.x >> 6, lane = threadIdx.x & 63;
    int e = blockIdx.x * 4 + g;
    int s = src[e], d = dst[e];
    float a = adjv[e];
    int f = lane * 4;
    float4 v = *(const float4*)&T[(size_t)s * 256 + f];
    atomicAdd(&O[(size_t)d * 256 + f + 0], a * v.x);
    atomicAdd(&O[(size_t)d * 256 + f + 1], a * v.y);
    atomicAdd(&O[(size_t)d * 256 + f + 2], a * v.z);
    atomicAdd(&O[(size_t)d * 256 + f + 3], a * v.w);
}

// Edge scatter (layer 1): O[dst] += w * bf2f(Y1[src, 0:256]), Y1 bf16 [65536,512]
__global__ __launch_bounds__(256)
void edge_scatter_bf16_kernel(const int* __restrict__ src, const int* __restrict__ dst,
                              const float* __restrict__ adjv,
                              const ushort* __restrict__ Y1, float* __restrict__ O)
{
    int g = threadIdx.x >> 6, lane = threadIdx.x & 63;
    int e = blockIdx.x * 4 + g;
    int s = src[e], d = dst[e];
    float a = adjv[e];
    int f = lane * 4;
    ushort4 v = *(const ushort4*)&Y1[(size_t)s * 512 + f];
    const ushort* vp = (const ushort*)&v;
    atomicAdd(&O[(size_t)d * 256 + f + 0], a * bf2f(vp[0]));
    atomicAdd(&O[(size_t)d * 256 + f + 1], a * bf2f(vp[1]));
    atomicAdd(&O[(size_t)d * 256 + f + 2], a * bf2f(vp[2]));
    atomicAdd(&O[(size_t)d * 256 + f + 3], a * bf2f(vp[3]));
}

// ---------------------------------------------------------------------------
// Final init: out[i,f] = bf2f(Y1[i, 256+f]) + R[i,f]   (ui1+Ui1_b + residual)
// ---------------------------------------------------------------------------
__global__ void final_init_kernel(const ushort* __restrict__ Y1, const float* __restrict__ R,
                                  float* __restrict__ out)
{
    size_t i4 = ((size_t)blockIdx.x * blockDim.x + threadIdx.x) * 4;
    if (i4 >= (size_t)V_NEXT * F_OUT) return;
    size_t row = i4 >> 8;
    int f = (int)(i4 & 255);
    ushort4 y = *(const ushort4*)&Y1[row * 512 + 256 + f];
    const ushort* yp = (const ushort*)&y;
    float4 r = *(const float4*)&R[i4];
    float4 o = make_float4(bf2f(yp[0]) + r.x, bf2f(yp[1]) + r.y,
                           bf2f(yp[2]) + r.z, bf2f(yp[3]) + r.w);
    *(float4*)&out[i4] = o;
}

// ---------------------------------------------------------------------------
// Host launcher
// ---------------------------------------------------------------------------
extern "C" void kernel_launch(void* const* d_in, const int* in_sizes, int n_in,
                              void* d_out, int out_size, void* d_ws, size_t ws_size,
                              hipStream_t stream)
{
    const float* x      = (const float*)d_in[0];
    const int*   up_row = (const int*)  d_in[1];
    const int*   up_col = (const int*)  d_in[2];
    const float* up_val = (const float*)d_in[3];
    const int*   e_src  = (const int*)  d_in[4];
    const int*   e_dst  = (const int*)  d_in[5];
    const float* adjv   = (const float*)d_in[6];
    const float* W_res  = (const float*)d_in[7];
    const float* b_res  = (const float*)d_in[8];
    const float* bn0_g  = (const float*)d_in[9];
    const float* bn0_b  = (const float*)d_in[10];
    const float* bn1_g  = (const float*)d_in[11];
    const float* bn1_b  = (const float*)d_in[12];
    const float* Ui0_W  = (const float*)d_in[13];
    const float* Ui0_b  = (const float*)d_in[14];
    const float* Uj0_W  = (const float*)d_in[15];
    const float* Uj0_b  = (const float*)d_in[16];
    const float* Ui1_W  = (const float*)d_in[17];
    const float* Ui1_b  = (const float*)d_in[18];
    const float* Uj1_W  = (const float*)d_in[19];
    const float* Uj1_b  = (const float*)d_in[20];

    float* out = (float*)d_out;

    // ---- workspace layout (bump allocator, 256B aligned) ----
    char* ws = (char*)d_ws;
    size_t off = 0;
    auto alloc = [&](size_t bytes) -> char* {
        char* p = ws + off;
        off = (off + bytes + 255) & ~(size_t)255;
        return p;
    };
    float*  Rbuf  = (float*) alloc((size_t)V_NEXT * F_OUT * 4);   // 67.1 MB
    float*  UJ0   = (float*) alloc((size_t)V_NEXT * F_OUT * 4);   // 67.1 MB (Y1 aliases this)
    float*  UI0   = (float*) alloc((size_t)V_NEXT * F_OUT * 4);   // 67.1 MB
    ushort* XB    = (ushort*)alloc((size_t)V_PREV * F_IN * 2);    // 16.8 MB (h1 aliases XB..XNB)
    ushort* XNB   = (ushort*)alloc((size_t)V_PREV * F_IN * 2);    // 16.8 MB
    ushort* XW    = (ushort*)alloc((size_t)V_PREV * F_OUT * 2);   // 8.4 MB
    ushort* XNU   = (ushort*)alloc((size_t)V_PREV * 512 * 2);     // 16.8 MB
    ushort* WresT = (ushort*)alloc(256 * 512 * 2);
    ushort* W0t   = (ushort*)alloc(512 * 512 * 2);
    ushort* W1t   = (ushort*)alloc(512 * 256 * 2);
    float*  bias1 = (float*) alloc(512 * 4);
    float*  psum0 = (float*) alloc(64 * 512 * 4);
    float*  psq0  = (float*) alloc(64 * 512 * 4);
    float*  mean0 = (float*) alloc(512 * 4);
    float*  rstd0 = (float*) alloc(512 * 4);
    float*  psum1 = (float*) alloc(256 * 256 * 4);
    float*  psq1  = (float*) alloc(256 * 256 * 4);
    float*  mean1 = (float*) alloc(256 * 4);
    float*  rstd1 = (float*) alloc(256 * 4);
    (void)ws_size; (void)in_sizes; (void)n_in; (void)out_size;

    // aliases (lifetimes disjoint):
    ushort* Y1 = (ushort*)UJ0;   // [65536,512] bf16, written after UJ0 is dead
    ushort* H1 = XB;             // [65536,256] bf16, written after XB/XNB are dead

    // ---- pipeline ----
    prep_weights_kernel<<<1024, 256, 0, stream>>>(W_res, Ui0_W, Uj0_W, Ui1_W, Uj1_W,
                                                  Ui1_b, Uj1_b, WresT, W0t, W1t, bias1);

    bn0_part_kernel<<<64, 256, 0, stream>>>(x, psum0, psq0);
    bn_finish_kernel<<<2, 256, 0, stream>>>(psum0, psq0, 64, 512, 1.0f / (V_PREV), mean0, rstd0);
    bn0_apply_kernel<<<8192, 256, 0, stream>>>(x, mean0, rstd0, bn0_g, bn0_b, XB, XNB);

    // XW = x @ W_res            [16384,256]
    gemm_bf16_kernel<<<dim3(2, 128), 256, 0, stream>>>(XB, WresT, XW, nullptr, V_PREV, 256, 512);
    // XNU = xn @ [Uj0|Ui0]      [16384,512]
    gemm_bf16_kernel<<<dim3(4, 128), 256, 0, stream>>>(XNB, W0t, XNU, nullptr, V_PREV, 512, 512);

    init_upbufs_kernel<<<16384, 256, 0, stream>>>(Rbuf, UJ0, UI0, b_res, Uj0_b, Ui0_b);
    up_scatter_kernel<<<NNZ_UP / 4, 256, 0, stream>>>(up_row, up_col, up_val, XNU, XW,
                                                      Rbuf, UJ0, UI0);

    // layer-0 edge aggregation: UI0 += adj * UJ0[src]
    edge_scatter_f32_kernel<<<N_EDGE / 4, 256, 0, stream>>>(e_src, e_dst, adjv, UJ0, UI0);

    bn1_part_kernel<<<256, 256, 0, stream>>>(UI0, psum1, psq1);
    bn_finish_kernel<<<1, 256, 0, stream>>>(psum1, psq1, 256, 256, 1.0f / (V_NEXT), mean1, rstd1);
    bn1_apply_kernel<<<16384, 256, 0, stream>>>(UI0, mean1, rstd1, bn1_g, bn1_b, H1);

    // Y1 = h1 @ [Uj1|Ui1] + [Uj1_b|Ui1_b]    [65536,512]
    gemm_bf16_kernel<<<dim3(4, 512), 256, 0, stream>>>(H1, W1t, Y1, bias1, V_NEXT, 512, 256);

    final_init_kernel<<<16384, 256, 0, stream>>>(Y1, Rbuf, out);
    edge_scatter_bf16_kernel<<<N_EDGE / 4, 256, 0, stream>>>(e_src, e_dst, adjv, Y1, out);
}

// Round 2
// 490.418 us; speedup vs baseline: 8.9722x; 8.9722x over previous
//
#include <hip/hip_runtime.h>

// ---------------------------------------------------------------------------
// Problem constants
// ---------------------------------------------------------------------------
#define V_PREV 16384
#define V_NEXT 65536
#define F_IN   512
#define F_OUT  256
#define NNZ_UP 65536
#define N_EDGE 524288

using f32x4 = __attribute__((ext_vector_type(4))) float;
using bfrag = __attribute__((ext_vector_type(8))) short;   // 8 x bf16

__device__ __forceinline__ ushort f2bf(float f) {
    union { float f; unsigned u; } v; v.f = f;
    unsigned r = (v.u + 0x7FFFu + ((v.u >> 16) & 1u)) >> 16;
    return (ushort)r;
}
__device__ __forceinline__ float bf2f(ushort h) {
    union { unsigned u; float f; } v; v.u = ((unsigned)h) << 16; return v.f;
}

// ---------------------------------------------------------------------------
// Weight prep (transpose + bf16, concat Uj|Ui)
// ---------------------------------------------------------------------------
__global__ void prep_weights_kernel(const float* __restrict__ Wres,
                                    const float* __restrict__ Ui0W, const float* __restrict__ Uj0W,
                                    const float* __restrict__ Ui1W, const float* __restrict__ Uj1W,
                                    const float* __restrict__ Ui1b, const float* __restrict__ Uj1b,
                                    ushort* __restrict__ WresT, ushort* __restrict__ W0t,
                                    ushort* __restrict__ W1t, float* __restrict__ bias1)
{
    int i = blockIdx.x * blockDim.x + threadIdx.x;   // 0 .. 512*512-1
    if (i < 256 * 512) {
        int n = i / 512, k = i % 512;
        WresT[i] = f2bf(Wres[k * 256 + n]);
    }
    if (i < 512 * 512) {
        int n = i / 512, k = i % 512;
        W0t[i] = f2bf(n < 256 ? Uj0W[k * 256 + n] : Ui0W[k * 256 + (n - 256)]);
    }
    if (i < 512 * 256) {
        int n = i / 256, k = i % 256;
        W1t[i] = f2bf(n < 256 ? Uj1W[k * 256 + n] : Ui1W[k * 256 + (n - 256)]);
    }
    if (i < 512) bias1[i] = (i < 256) ? Uj1b[i] : Ui1b[i - 256];
}

// ---------------------------------------------------------------------------
// CSR build: histogram -> 2-level exclusive scan -> fill (dst-sorted src/val)
// ---------------------------------------------------------------------------
__global__ void zero_int_kernel(int* __restrict__ p, int n) {
    int i = blockIdx.x * blockDim.x + threadIdx.x;
    if (i < n) p[i] = 0;
}

__global__ void hist_kernel(const int* __restrict__ dst, int* __restrict__ cnt) {
    int e = blockIdx.x * blockDim.x + threadIdx.x;   // grid covers N_EDGE exactly
    atomicAdd(&cnt[dst[e]], 1);
}

__global__ void scan_block_kernel(const int* __restrict__ cnt, int* __restrict__ offs,
                                  int* __restrict__ bsum)
{
    __shared__ int buf[2][256];
    int t = threadIdx.x;
    int i = blockIdx.x * 256 + t;
    int v = cnt[i];
    int p = 0;
    buf[0][t] = v;
    __syncthreads();
    for (int d = 1; d < 256; d <<= 1) {
        int nv = buf[p][t] + ((t >= d) ? buf[p][t - d] : 0);
        buf[p ^ 1][t] = nv;
        p ^= 1;
        __syncthreads();
    }
    int incl = buf[p][t];
    offs[i] = incl - v;                 // exclusive within block
    if (t == 255) bsum[blockIdx.x] = incl;
}

__global__ void scan_top_kernel(const int* __restrict__ bsum, int* __restrict__ boff)
{
    __shared__ int buf[2][256];
    int t = threadIdx.x;
    int v = bsum[t];
    int p = 0;
    buf[0][t] = v;
    __syncthreads();
    for (int d = 1; d < 256; d <<= 1) {
        int nv = buf[p][t] + ((t >= d) ? buf[p][t - d] : 0);
        buf[p ^ 1][t] = nv;
        p ^= 1;
        __syncthreads();
    }
    boff[t] = buf[p][t] - v;            // exclusive
}

__global__ void add_offs_kernel(int* __restrict__ offs, const int* __restrict__ boff,
                                int* __restrict__ cursor)
{
    int i = blockIdx.x * 256 + threadIdx.x;
    int o = offs[i] + boff[blockIdx.x];
    offs[i] = o;
    cursor[i] = o;
}

__global__ void fill_kernel(const int* __restrict__ src, const int* __restrict__ dst,
                            const float* __restrict__ adjv,
                            int* __restrict__ cursor, int* __restrict__ srcs,
                            float* __restrict__ vals)
{
    int e = blockIdx.x * blockDim.x + threadIdx.x;
    int d = dst[e];
    int p = atomicAdd(&cursor[d], 1);
    srcs[p] = src[e];
    vals[p] = adjv[e];
}

// ---------------------------------------------------------------------------
// BatchNorm stats
// ---------------------------------------------------------------------------
__global__ void bn0_part_kernel(const float* __restrict__ x,
                                float* __restrict__ psum, float* __restrict__ psq)
{
    int blk = blockIdx.x, t = threadIdx.x;
    float s0 = 0, s1 = 0, q0 = 0, q1 = 0;
    for (int r = 0; r < 256; r++) {
        size_t base = ((size_t)blk * 256 + r) * 512;
        float a = x[base + t], b = x[base + t + 256];
        s0 += a; q0 += a * a; s1 += b; q1 += b * b;
    }
    psum[blk * 512 + t] = s0; psum[blk * 512 + t + 256] = s1;
    psq [blk * 512 + t] = q0; psq [blk * 512 + t + 256] = q1;
}

__global__ void bn1_part_bf16_kernel(const ushort* __restrict__ xx,
                                     float* __restrict__ psum, float* __restrict__ psq)
{
    int blk = blockIdx.x, t = threadIdx.x;
    float s = 0, q = 0;
    for (int r = 0; r < 256; r++) {
        float a = bf2f(xx[((size_t)blk * 256 + r) * 256 + t]);
        s += a; q += a * a;
    }
    psum[blk * 256 + t] = s; psq[blk * 256 + t] = q;
}

__global__ void bn_finish_kernel(const float* __restrict__ psum, const float* __restrict__ psq,
                                 int nblocks, int C, float invN,
                                 float* __restrict__ mean, float* __restrict__ rstd)
{
    int c = blockIdx.x * blockDim.x + threadIdx.x;
    if (c >= C) return;
    float s = 0, q = 0;
    for (int i = 0; i < nblocks; i++) { s += psum[i * C + c]; q += psq[i * C + c]; }
    float m = s * invN;
    float v = q * invN - m * m;
    mean[c] = m;
    rstd[c] = rsqrtf(v + 1e-5f);
}

// ---------------------------------------------------------------------------
// bn0 apply: xb = bf16(x), xnb = bf16(relu(bn0(x)))
// ---------------------------------------------------------------------------
__global__ void bn0_apply_kernel(const float* __restrict__ x,
                                 const float* __restrict__ mean, const float* __restrict__ rstd,
                                 const float* __restrict__ g, const float* __restrict__ b,
                                 ushort* __restrict__ xb, ushort* __restrict__ xnb)
{
    size_t i4 = ((size_t)blockIdx.x * blockDim.x + threadIdx.x) * 4;
    if (i4 >= (size_t)V_PREV * F_IN) return;
    float4 v = *(const float4*)&x[i4];
    int c = (int)(i4 & 511);
    float vv[4] = { v.x, v.y, v.z, v.w };
    ushort xs[4], ns[4];
#pragma unroll
    for (int j = 0; j < 4; j++) {
        int cc = c + j;
        float t = (vv[j] - mean[cc]) * rstd[cc] * g[cc] + b[cc];
        t = fmaxf(t, 0.0f);
        xs[j] = f2bf(vv[j]);
        ns[j] = f2bf(t);
    }
    *(ushort4*)&xb[i4]  = make_ushort4(xs[0], xs[1], xs[2], xs[3]);
    *(ushort4*)&xnb[i4] = make_ushort4(ns[0], ns[1], ns[2], ns[3]);
}

// bn1 apply: h1 = bf16(relu(bn1(x1)))  over [65536,256], x1 bf16
__global__ void bn1_apply_bf16_kernel(const ushort* __restrict__ xx,
                                      const float* __restrict__ mean, const float* __restrict__ rstd,
                                      const float* __restrict__ g, const float* __restrict__ b,
                                      ushort* __restrict__ h1)
{
    size_t i4 = ((size_t)blockIdx.x * blockDim.x + threadIdx.x) * 4;
    if (i4 >= (size_t)V_NEXT * F_OUT) return;
    ushort4 v = *(const ushort4*)&xx[i4];
    const ushort* vp = (const ushort*)&v;
    int c = (int)(i4 & 255);
    ushort ns[4];
#pragma unroll
    for (int j = 0; j < 4; j++) {
        int cc = c + j;
        float t = (bf2f(vp[j]) - mean[cc]) * rstd[cc] * g[cc] + b[cc];
        ns[j] = f2bf(fmaxf(t, 0.0f));
    }
    *(ushort4*)&h1[i4] = make_ushort4(ns[0], ns[1], ns[2], ns[3]);
}

// ---------------------------------------------------------------------------
// bf16 GEMM: C[M,N] (bf16) = A[M,K] @ Bt[N,K]^T  (+ bias[N])
// 128x128 tile, BK=32, 4 waves (2x2), mfma 16x16x32.
// ---------------------------------------------------------------------------
__global__ __launch_bounds__(256)
void gemm_bf16_kernel(const ushort* __restrict__ A, const ushort* __restrict__ Bt,
                      ushort* __restrict__ C, const float* __restrict__ bias,
                      int M, int N, int K)
{
    __shared__ ushort As[128 * 40];
    __shared__ ushort Bs[128 * 40];

    const int tid  = threadIdx.x;
    const int lane = tid & 63;
    const int wave = tid >> 6;
    const int wm = wave >> 1, wn = wave & 1;
    const int lr = lane & 15, lg = lane >> 4;
    const int tM = blockIdx.y * 128, tN = blockIdx.x * 128;

    const int r0 = tid >> 2;
    const int s0 = (tid & 3) * 8;

    f32x4 acc[4][4] = {};

    for (int k0 = 0; k0 < K; k0 += 32) {
        *(uint4*)&As[(r0     ) * 40 + s0] = *(const uint4*)&A[(size_t)(tM + r0     ) * K + k0 + s0];
        *(uint4*)&As[(r0 + 64) * 40 + s0] = *(const uint4*)&A[(size_t)(tM + r0 + 64) * K + k0 + s0];
        *(uint4*)&Bs[(r0     ) * 40 + s0] = *(const uint4*)&Bt[(size_t)(tN + r0     ) * K + k0 + s0];
        *(uint4*)&Bs[(r0 + 64) * 40 + s0] = *(const uint4*)&Bt[(size_t)(tN + r0 + 64) * K + k0 + s0];
        __syncthreads();

        bfrag af[4], bfv[4];
#pragma unroll
        for (int mm = 0; mm < 4; mm++)
            af[mm] = *(const bfrag*)&As[(wm * 64 + mm * 16 + lr) * 40 + lg * 8];
#pragma unroll
        for (int nn = 0; nn < 4; nn++)
            bfv[nn] = *(const bfrag*)&Bs[(wn * 64 + nn * 16 + lr) * 40 + lg * 8];
#pragma unroll
        for (int mm = 0; mm < 4; mm++)
#pragma unroll
            for (int nn = 0; nn < 4; nn++)
                acc[mm][nn] = __builtin_amdgcn_mfma_f32_16x16x32_bf16(af[mm], bfv[nn], acc[mm][nn], 0, 0, 0);
        __syncthreads();
    }

#pragma unroll
    for (int mm = 0; mm < 4; mm++) {
#pragma unroll
        for (int nn = 0; nn < 4; nn++) {
#pragma unroll
            for (int r = 0; r < 4; r++) {
                int row = tM + wm * 64 + mm * 16 + lg * 4 + r;
                int col = tN + wn * 64 + nn * 16 + lr;
                float v = acc[mm][nn][r];
                if (bias) v += bias[col];
                C[(size_t)row * N + col] = f2bf(v);
            }
        }
    }
}

// ---------------------------------------------------------------------------
// Upsample direct (up_row covers every row exactly once -> plain stores):
//   R  [r] = bf16(b_res + s*XW [c])
//   UJb[r] = bf16(uj0_b + s*XNU[c, 0:256])    (= Uj0(h)+b, the gathered message src)
//   UIh[r] = bf16(ui0_b + s*XNU[c, 256:512])  (= Ui0(h)+b, the self term)
// ---------------------------------------------------------------------------
__global__ __launch_bounds__(256)
void up_direct_kernel(const int* __restrict__ up_row, const int* __restrict__ up_col,
                      const float* __restrict__ up_val,
                      const ushort* __restrict__ XNU, const ushort* __restrict__ XW,
                      const float* __restrict__ b_res,
                      const float* __restrict__ uj_b, const float* __restrict__ ui_b,
                      ushort* __restrict__ R, ushort* __restrict__ UJb, ushort* __restrict__ UIh)
{
    int k = blockIdx.x * 4 + (threadIdx.x >> 6);
    int f = (threadIdx.x & 63) * 4;
    int r = up_row[k], c = up_col[k];
    float s = up_val[k];
    ushort4 xw = *(const ushort4*)&XW [(size_t)c * 256 + f];
    ushort4 uj = *(const ushort4*)&XNU[(size_t)c * 512 + f];
    ushort4 ui = *(const ushort4*)&XNU[(size_t)c * 512 + 256 + f];
    const ushort* xwp = (const ushort*)&xw;
    const ushort* ujp = (const ushort*)&uj;
    const ushort* uip = (const ushort*)&ui;
    ushort ro[4], jo[4], io[4];
#pragma unroll
    for (int j = 0; j < 4; j++) {
        ro[j] = f2bf(b_res[f + j] + s * bf2f(xwp[j]));
        jo[j] = f2bf(uj_b[f + j]  + s * bf2f(ujp[j]));
        io[j] = f2bf(ui_b[f + j]  + s * bf2f(uip[j]));
    }
    *(ushort4*)&R  [(size_t)r * 256 + f] = make_ushort4(ro[0], ro[1], ro[2], ro[3]);
    *(ushort4*)&UJb[(size_t)r * 256 + f] = make_ushort4(jo[0], jo[1], jo[2], jo[3]);
    *(ushort4*)&UIh[(size_t)r * 256 + f] = make_ushort4(io[0], io[1], io[2], io[3]);
}

// ---------------------------------------------------------------------------
// Edge gather layer 0: X1[d] = UIh[d] + sum_e val*UJb[src]   (one wave per d)
// ---------------------------------------------------------------------------
__global__ __launch_bounds__(256)
void gather0_kernel(const int* __restrict__ offs, const int* __restrict__ cnt,
                    const int* __restrict__ srcs, const float* __restrict__ vals,
                    const ushort* __restrict__ UIh, const ushort* __restrict__ UJb,
                    ushort* __restrict__ X1)
{
    int d = blockIdx.x * 4 + (threadIdx.x >> 6);
    int f = (threadIdx.x & 63) * 4;
    ushort4 b4 = *(const ushort4*)&UIh[(size_t)d * 256 + f];
    const ushort* bp = (const ushort*)&b4;
    float acc0 = bf2f(bp[0]), acc1 = bf2f(bp[1]), acc2 = bf2f(bp[2]), acc3 = bf2f(bp[3]);
    int st = offs[d], en = st + cnt[d];
    for (int e = st; e < en; e++) {
        int s = srcs[e];
        float a = vals[e];
        ushort4 v = *(const ushort4*)&UJb[(size_t)s * 256 + f];
        const ushort* vp = (const ushort*)&v;
        acc0 += a * bf2f(vp[0]); acc1 += a * bf2f(vp[1]);
        acc2 += a * bf2f(vp[2]); acc3 += a * bf2f(vp[3]);
    }
    *(ushort4*)&X1[(size_t)d * 256 + f] =
        make_ushort4(f2bf(acc0), f2bf(acc1), f2bf(acc2), f2bf(acc3));
}

// ---------------------------------------------------------------------------
// Edge gather layer 1 + residual: out[d] = R[d] + Y1[d,256:512] + sum val*Y1[src,0:256]
// ---------------------------------------------------------------------------
__global__ __launch_bounds__(256)
void gather1_kernel(const int* __restrict__ offs, const int* __restrict__ cnt,
                    const int* __restrict__ srcs, const float* __restrict__ vals,
                    const ushort* __restrict__ Y1, const ushort* __restrict__ R,
                    float* __restrict__ out)
{
    int d = blockIdx.x * 4 + (threadIdx.x >> 6);
    int f = (threadIdx.x & 63) * 4;
    ushort4 r4 = *(const ushort4*)&R [(size_t)d * 256 + f];
    ushort4 u4 = *(const ushort4*)&Y1[(size_t)d * 512 + 256 + f];
    const ushort* rp = (const ushort*)&r4;
    const ushort* up = (const ushort*)&u4;
    float acc0 = bf2f(rp[0]) + bf2f(up[0]);
    float acc1 = bf2f(rp[1]) + bf2f(up[1]);
    float acc2 = bf2f(rp[2]) + bf2f(up[2]);
    float acc3 = bf2f(rp[3]) + bf2f(up[3]);
    int st = offs[d], en = st + cnt[d];
    for (int e = st; e < en; e++) {
        int s = srcs[e];
        float a = vals[e];
        ushort4 v = *(const ushort4*)&Y1[(size_t)s * 512 + f];
        const ushort* vp = (const ushort*)&v;
        acc0 += a * bf2f(vp[0]); acc1 += a * bf2f(vp[1]);
        acc2 += a * bf2f(vp[2]); acc3 += a * bf2f(vp[3]);
    }
    *(float4*)&out[(size_t)d * 256 + f] = make_float4(acc0, acc1, acc2, acc3);
}

// ---------------------------------------------------------------------------
// Host launcher
// ---------------------------------------------------------------------------
extern "C" void kernel_launch(void* const* d_in, const int* in_sizes, int n_in,
                              void* d_out, int out_size, void* d_ws, size_t ws_size,
                              hipStream_t stream)
{
    const float* x      = (const float*)d_in[0];
    const int*   up_row = (const int*)  d_in[1];
    const int*   up_col = (const int*)  d_in[2];
    const float* up_val = (const float*)d_in[3];
    const int*   e_src  = (const int*)  d_in[4];
    const int*   e_dst  = (const int*)  d_in[5];
    const float* adjv   = (const float*)d_in[6];
    const float* W_res  = (const float*)d_in[7];
    const float* b_res  = (const float*)d_in[8];
    const float* bn0_g  = (const float*)d_in[9];
    const float* bn0_b  = (const float*)d_in[10];
    const float* bn1_g  = (const float*)d_in[11];
    const float* bn1_b  = (const float*)d_in[12];
    const float* Ui0_W  = (const float*)d_in[13];
    const float* Ui0_b  = (const float*)d_in[14];
    const float* Uj0_W  = (const float*)d_in[15];
    const float* Uj0_b  = (const float*)d_in[16];
    const float* Ui1_W  = (const float*)d_in[17];
    const float* Ui1_b  = (const float*)d_in[18];
    const float* Uj1_W  = (const float*)d_in[19];
    const float* Uj1_b  = (const float*)d_in[20];

    float* out = (float*)d_out;

    // ---- workspace layout (bump allocator, 256B aligned) ----
    char* ws = (char*)d_ws;
    size_t off = 0;
    auto alloc = [&](size_t bytes) -> char* {
        char* p = ws + off;
        off = (off + bytes + 255) & ~(size_t)255;
        return p;
    };
    ushort* XB    = (ushort*)alloc((size_t)V_PREV * F_IN * 2);    // 16.8 MB \ X1 aliases
    ushort* XNB   = (ushort*)alloc((size_t)V_PREV * F_IN * 2);    // 16.8 MB /  XB..XNB
    ushort* XW    = (ushort*)alloc((size_t)V_PREV * F_OUT * 2);   // 8.4 MB
    ushort* XNU   = (ushort*)alloc((size_t)V_PREV * 512 * 2);     // 16.8 MB
    ushort* Rb    = (ushort*)alloc((size_t)V_NEXT * F_OUT * 2);   // 33.6 MB
    ushort* UJb   = (ushort*)alloc((size_t)V_NEXT * F_OUT * 2);   // 33.6 MB
    ushort* UIh   = (ushort*)alloc((size_t)V_NEXT * F_OUT * 2);   // 33.6 MB (H1 aliases)
    ushort* Y1    = (ushort*)alloc((size_t)V_NEXT * 512 * 2);     // 67.1 MB
    int*    cnt   = (int*)   alloc(V_NEXT * 4);
    int*    offs  = (int*)   alloc(V_NEXT * 4);
    int*    cursor= (int*)   alloc(V_NEXT * 4);
    int*    bsum  = (int*)   alloc(256 * 4);
    int*    boff  = (int*)   alloc(256 * 4);
    int*    srcs  = (int*)   alloc((size_t)N_EDGE * 4);           // 2.1 MB
    float*  vals  = (float*) alloc((size_t)N_EDGE * 4);           // 2.1 MB
    ushort* WresT = (ushort*)alloc(256 * 512 * 2);
    ushort* W0t   = (ushort*)alloc(512 * 512 * 2);
    ushort* W1t   = (ushort*)alloc(512 * 256 * 2);
    float*  bias1 = (float*) alloc(512 * 4);
    float*  psum0 = (float*) alloc(64 * 512 * 4);
    float*  psq0  = (float*) alloc(64 * 512 * 4);
    float*  mean0 = (float*) alloc(512 * 4);
    float*  rstd0 = (float*) alloc(512 * 4);
    float*  psum1 = (float*) alloc(256 * 256 * 4);
    float*  psq1  = (float*) alloc(256 * 256 * 4);
    float*  mean1 = (float*) alloc(256 * 4);
    float*  rstd1 = (float*) alloc(256 * 4);
    (void)ws_size; (void)in_sizes; (void)n_in; (void)out_size;

    // aliases (lifetimes disjoint)
    ushort* X1 = XB;     // [65536,256] bf16: written after XB/XNB consumed by GEMMs
    ushort* H1 = UIh;    // [65536,256] bf16: written after UIh consumed by gather0

    // ---- CSR build (shared by both ECC layers) ----
    prep_weights_kernel<<<1024, 256, 0, stream>>>(W_res, Ui0_W, Uj0_W, Ui1_W, Uj1_W,
                                                  Ui1_b, Uj1_b, WresT, W0t, W1t, bias1);
    zero_int_kernel<<<256, 256, 0, stream>>>(cnt, V_NEXT);
    hist_kernel<<<N_EDGE / 256, 256, 0, stream>>>(e_dst, cnt);
    scan_block_kernel<<<256, 256, 0, stream>>>(cnt, offs, bsum);
    scan_top_kernel<<<1, 256, 0, stream>>>(bsum, boff);
    add_offs_kernel<<<256, 256, 0, stream>>>(offs, boff, cursor);
    fill_kernel<<<N_EDGE / 256, 256, 0, stream>>>(e_src, e_dst, adjv, cursor, srcs, vals);

    // ---- bn0 + bf16 casts ----
    bn0_part_kernel<<<64, 256, 0, stream>>>(x, psum0, psq0);
    bn_finish_kernel<<<2, 256, 0, stream>>>(psum0, psq0, 64, 512, 1.0f / V_PREV, mean0, rstd0);
    bn0_apply_kernel<<<8192, 256, 0, stream>>>(x, mean0, rstd0, bn0_g, bn0_b, XB, XNB);

    // ---- V_PREV-level GEMMs (4x fewer FLOPs than post-upsample) ----
    gemm_bf16_kernel<<<dim3(2, 128), 256, 0, stream>>>(XB,  WresT, XW,  nullptr, V_PREV, 256, 512);
    gemm_bf16_kernel<<<dim3(4, 128), 256, 0, stream>>>(XNB, W0t,   XNU, nullptr, V_PREV, 512, 512);

    // ---- upsample (direct, rows unique) ----
    up_direct_kernel<<<NNZ_UP / 4, 256, 0, stream>>>(up_row, up_col, up_val, XNU, XW,
                                                     b_res, Uj0_b, Ui0_b, Rb, UJb, UIh);

    // ---- ECC layer 0 aggregation (gather) ----
    gather0_kernel<<<V_NEXT / 4, 256, 0, stream>>>(offs, cnt, srcs, vals, UIh, UJb, X1);

    // ---- bn1 ----
    bn1_part_bf16_kernel<<<256, 256, 0, stream>>>(X1, psum1, psq1);
    bn_finish_kernel<<<1, 256, 0, stream>>>(psum1, psq1, 256, 256, 1.0f / V_NEXT, mean1, rstd1);
    bn1_apply_bf16_kernel<<<16384, 256, 0, stream>>>(X1, mean1, rstd1, bn1_g, bn1_b, H1);

    // ---- ECC layer 1 GEMM: Y1 = H1 @ [Uj1|Ui1] + [Uj1_b|Ui1_b] ----
    gemm_bf16_kernel<<<dim3(4, 512), 256, 0, stream>>>(H1, W1t, Y1, bias1, V_NEXT, 512, 256);

    // ---- ECC layer 1 aggregation + residual + output ----
    gather1_kernel<<<V_NEXT / 4, 256, 0, stream>>>(offs, cnt, srcs, vals, Y1, Rb, out);
}

// Round 3
// 472.936 us; speedup vs baseline: 9.3038x; 1.0370x over previous
//
#include <hip/hip_runtime.h>

// ---------------------------------------------------------------------------
// Problem constants
// ---------------------------------------------------------------------------
#define V_PREV 16384
#define V_NEXT 65536
#define F_IN   512
#define F_OUT  256
#define NNZ_UP 65536
#define N_EDGE 524288

using f32x4 = __attribute__((ext_vector_type(4))) float;
using bfrag = __attribute__((ext_vector_type(8))) short;   // 8 x bf16

__device__ __forceinline__ ushort f2bf(float f) {
    union { float f; unsigned u; } v; v.f = f;
    unsigned r = (v.u + 0x7FFFu + ((v.u >> 16) & 1u)) >> 16;
    return (ushort)r;
}
__device__ __forceinline__ float bf2f(ushort h) {
    union { unsigned u; float f; } v; v.u = ((unsigned)h) << 16; return v.f;
}

// ---------------------------------------------------------------------------
// Weight prep (transpose + bf16, concat Uj|Ui; bias1 Ui-half folds b_res)
// ---------------------------------------------------------------------------
__global__ void prep_weights_kernel(const float* __restrict__ Wres,
                                    const float* __restrict__ Ui0W, const float* __restrict__ Uj0W,
                                    const float* __restrict__ Ui1W, const float* __restrict__ Uj1W,
                                    const float* __restrict__ Ui1b, const float* __restrict__ Uj1b,
                                    const float* __restrict__ bres,
                                    ushort* __restrict__ WresT, ushort* __restrict__ W0t,
                                    ushort* __restrict__ W1t, float* __restrict__ bias1)
{
    int i = blockIdx.x * blockDim.x + threadIdx.x;   // 0 .. 512*512-1
    if (i < 256 * 512) {
        int n = i / 512, k = i % 512;
        WresT[i] = f2bf(Wres[k * 256 + n]);
    }
    if (i < 512 * 512) {
        int n = i / 512, k = i % 512;
        W0t[i] = f2bf(n < 256 ? Uj0W[k * 256 + n] : Ui0W[k * 256 + (n - 256)]);
    }
    if (i < 512 * 256) {
        int n = i / 256, k = i % 256;
        W1t[i] = f2bf(n < 256 ? Uj1W[k * 256 + n] : Ui1W[k * 256 + (n - 256)]);
    }
    if (i < 512) bias1[i] = (i < 256) ? Uj1b[i] : (Ui1b[i - 256] + bres[i - 256]);
}

// ---------------------------------------------------------------------------
// CSR build: histogram -> 2-level exclusive scan -> fill (dst-sorted src/val)
// ---------------------------------------------------------------------------
__global__ void hist_kernel(const int* __restrict__ dst, int* __restrict__ cnt) {
    int e = blockIdx.x * blockDim.x + threadIdx.x;
    atomicAdd(&cnt[dst[e]], 1);
}

__global__ void scan_block_kernel(const int* __restrict__ cnt, int* __restrict__ offs,
                                  int* __restrict__ bsum)
{
    __shared__ int buf[2][256];
    int t = threadIdx.x;
    int i = blockIdx.x * 256 + t;
    int v = cnt[i];
    int p = 0;
    buf[0][t] = v;
    __syncthreads();
    for (int d = 1; d < 256; d <<= 1) {
        int nv = buf[p][t] + ((t >= d) ? buf[p][t - d] : 0);
        buf[p ^ 1][t] = nv;
        p ^= 1;
        __syncthreads();
    }
    int incl = buf[p][t];
    offs[i] = incl - v;
    if (t == 255) bsum[blockIdx.x] = incl;
}

__global__ void scan_top_kernel(const int* __restrict__ bsum, int* __restrict__ boff)
{
    __shared__ int buf[2][256];
    int t = threadIdx.x;
    int v = bsum[t];
    int p = 0;
    buf[0][t] = v;
    __syncthreads();
    for (int d = 1; d < 256; d <<= 1) {
        int nv = buf[p][t] + ((t >= d) ? buf[p][t - d] : 0);
        buf[p ^ 1][t] = nv;
        p ^= 1;
        __syncthreads();
    }
    boff[t] = buf[p][t] - v;
}

__global__ void add_offs_kernel(int* __restrict__ offs, const int* __restrict__ boff,
                                int* __restrict__ cursor)
{
    int i = blockIdx.x * 256 + threadIdx.x;
    int o = offs[i] + boff[blockIdx.x];
    offs[i] = o;
    cursor[i] = o;
}

__global__ void fill_kernel(const int* __restrict__ src, const int* __restrict__ dst,
                            const float* __restrict__ adjv,
                            int* __restrict__ cursor, int* __restrict__ srcs,
                            float* __restrict__ vals)
{
    int e = blockIdx.x * blockDim.x + threadIdx.x;
    int d = dst[e];
    int p = atomicAdd(&cursor[d], 1);
    srcs[p] = src[e];
    vals[p] = adjv[e];
}

// Invert the up map: colof[up_row[k]] = up_col[k], valof[up_row[k]] = up_val[k]
__global__ void invert_up_kernel(const int* __restrict__ up_row, const int* __restrict__ up_col,
                                 const float* __restrict__ up_val,
                                 int* __restrict__ colof, float* __restrict__ valof)
{
    int k = blockIdx.x * blockDim.x + threadIdx.x;
    int r = up_row[k];
    colof[r] = up_col[k];
    valof[r] = up_val[k];
}

// ---------------------------------------------------------------------------
// BatchNorm stats
// ---------------------------------------------------------------------------
__global__ void bn0_part_kernel(const float* __restrict__ x,
                                float* __restrict__ psum, float* __restrict__ psq)
{
    int blk = blockIdx.x, t = threadIdx.x;
    float s0 = 0, s1 = 0, q0 = 0, q1 = 0;
    for (int r = 0; r < 256; r++) {
        size_t base = ((size_t)blk * 256 + r) * 512;
        float a = x[base + t], b = x[base + t + 256];
        s0 += a; q0 += a * a; s1 += b; q1 += b * b;
    }
    psum[blk * 512 + t] = s0; psum[blk * 512 + t + 256] = s1;
    psq [blk * 512 + t] = q0; psq [blk * 512 + t + 256] = q1;
}

// X1 bf16 [65536,256]; 512 blocks x 128 rows
__global__ void bn1_part_bf16_kernel(const ushort* __restrict__ xx,
                                     float* __restrict__ psum, float* __restrict__ psq)
{
    int blk = blockIdx.x, t = threadIdx.x;
    float s = 0, q = 0;
    for (int r = 0; r < 128; r++) {
        float a = bf2f(xx[((size_t)blk * 128 + r) * 256 + t]);
        s += a; q += a * a;
    }
    psum[blk * 256 + t] = s; psq[blk * 256 + t] = q;
}

// produces per-channel affine: sc = g*rstd, sh = b - mean*sc
__global__ void bn_finish_kernel(const float* __restrict__ psum, const float* __restrict__ psq,
                                 int nblocks, int C, float invN,
                                 const float* __restrict__ g, const float* __restrict__ b,
                                 float* __restrict__ sc, float* __restrict__ sh)
{
    int c = blockIdx.x * blockDim.x + threadIdx.x;
    if (c >= C) return;
    float s = 0, q = 0;
    for (int i = 0; i < nblocks; i++) { s += psum[i * C + c]; q += psq[i * C + c]; }
    float m = s * invN;
    float v = q * invN - m * m;
    float r = rsqrtf(v + 1e-5f);
    float scale = r * g[c];
    sc[c] = scale;
    sh[c] = b[c] - m * scale;
}

// ---------------------------------------------------------------------------
// GEMM0 fused: reads x f32 [16384,512] directly.
//   blocks bx<2:  XW  = bf16(x) @ WresT^T          (raw A)
//   blocks bx>=2: XNU = bf16(relu(bn0(x))) @ W0t^T (bn A)
// 128x128 tile, BK=32, 4 waves (2x2), mfma 16x16x32.
// ---------------------------------------------------------------------------
__global__ __launch_bounds__(256)
void gemm0_fused_kernel(const float* __restrict__ x,
                        const ushort* __restrict__ WresT, const ushort* __restrict__ W0t,
                        const float* __restrict__ sc0, const float* __restrict__ sh0,
                        ushort* __restrict__ XW, ushort* __restrict__ XNU)
{
    __shared__ ushort As[128 * 40];
    __shared__ ushort Bs[128 * 40];
    __shared__ float s_sc[512], s_sh[512];

    const int tid = threadIdx.x;
    const bool bnmode = blockIdx.x >= 2;
    const ushort* Bt = bnmode ? W0t : WresT;
    const int tN  = blockIdx.x * 128;
    const int tNl = bnmode ? tN - 256 : tN;
    const int Nout = bnmode ? 512 : 256;
    ushort* Cout = bnmode ? XNU : XW;
    const int tM = blockIdx.y * 128;

    for (int i = tid; i < 512; i += 256) { s_sc[i] = sc0[i]; s_sh[i] = sh0[i]; }
    __syncthreads();

    const int lane = tid & 63;
    const int wave = tid >> 6;
    const int wm = wave >> 1, wn = wave & 1;
    const int lr = lane & 15, lg = lane >> 4;

    const int ra = tid >> 1;            // A-stage row 0..127
    const int sa = (tid & 1) * 16;      // A-stage col 0 or 16
    const int rb = tid >> 2;            // B-stage row 0..63
    const int sb = (tid & 3) * 8;       // B-stage col 0,8,16,24

    f32x4 acc[4][4] = {};

    for (int k0 = 0; k0 < 512; k0 += 32) {
        // --- A stage: 16 f32 -> bf16 (optional bn+relu) ---
        const float* xp = &x[(size_t)(tM + ra) * 512 + k0 + sa];
        float4 f0 = *(const float4*)(xp);
        float4 f1 = *(const float4*)(xp + 4);
        float4 f2 = *(const float4*)(xp + 8);
        float4 f3 = *(const float4*)(xp + 12);
        float vv[16] = { f0.x,f0.y,f0.z,f0.w, f1.x,f1.y,f1.z,f1.w,
                         f2.x,f2.y,f2.z,f2.w, f3.x,f3.y,f3.z,f3.w };
        ushort hh[16];
        if (bnmode) {
#pragma unroll
            for (int j = 0; j < 16; j++) {
                int c = k0 + sa + j;
                hh[j] = f2bf(fmaxf(vv[j] * s_sc[c] + s_sh[c], 0.0f));
            }
        } else {
#pragma unroll
            for (int j = 0; j < 16; j++) hh[j] = f2bf(vv[j]);
        }
        *(uint4*)&As[ra * 40 + sa]     = *(uint4*)&hh[0];
        *(uint4*)&As[ra * 40 + sa + 8] = *(uint4*)&hh[8];

        // --- B stage ---
        *(uint4*)&Bs[(rb     ) * 40 + sb] = *(const uint4*)&Bt[(size_t)(tNl + rb     ) * 512 + k0 + sb];
        *(uint4*)&Bs[(rb + 64) * 40 + sb] = *(const uint4*)&Bt[(size_t)(tNl + rb + 64) * 512 + k0 + sb];
        __syncthreads();

        bfrag af[4], bfv[4];
#pragma unroll
        for (int mm = 0; mm < 4; mm++)
            af[mm] = *(const bfrag*)&As[(wm * 64 + mm * 16 + lr) * 40 + lg * 8];
#pragma unroll
        for (int nn = 0; nn < 4; nn++)
            bfv[nn] = *(const bfrag*)&Bs[(wn * 64 + nn * 16 + lr) * 40 + lg * 8];
#pragma unroll
        for (int mm = 0; mm < 4; mm++)
#pragma unroll
            for (int nn = 0; nn < 4; nn++)
                acc[mm][nn] = __builtin_amdgcn_mfma_f32_16x16x32_bf16(af[mm], bfv[nn], acc[mm][nn], 0, 0, 0);
        __syncthreads();
    }

#pragma unroll
    for (int mm = 0; mm < 4; mm++)
#pragma unroll
        for (int nn = 0; nn < 4; nn++)
#pragma unroll
            for (int r = 0; r < 4; r++) {
                int row = tM + wm * 64 + mm * 16 + lg * 4 + r;
                int col = tNl + wn * 64 + nn * 16 + lr;
                Cout[(size_t)row * Nout + col] = f2bf(acc[mm][nn][r]);
            }
}

// ---------------------------------------------------------------------------
// GEMM1 fused: A = relu(bn1(X1)) applied in staging; Bt = W1t [512][256].
//   bx<2 : YJ  (bf16) = A @ Uj1 + Uj1_b                (the gathered table)
//   bx>=2: out (f32)  = A @ Ui1 + (Ui1_b + b_res) + up_val*XW[up_col] (residual)
// ---------------------------------------------------------------------------
__global__ __launch_bounds__(256)
void gemm1_fused_kernel(const ushort* __restrict__ X1, const ushort* __restrict__ W1t,
                        const float* __restrict__ sc1, const float* __restrict__ sh1,
                        const float* __restrict__ bias1,
                        const int* __restrict__ colof, const float* __restrict__ valof,
                        const ushort* __restrict__ XW,
                        ushort* __restrict__ YJ, float* __restrict__ out)
{
    __shared__ ushort As[128 * 40];
    __shared__ ushort Bs[128 * 40];
    __shared__ float s_sc[256], s_sh[256];

    const int tid = threadIdx.x;
    for (int i = tid; i < 256; i += 256) { s_sc[i] = sc1[i]; s_sh[i] = sh1[i]; }
    __syncthreads();

    const int lane = tid & 63;
    const int wave = tid >> 6;
    const int wm = wave >> 1, wn = wave & 1;
    const int lr = lane & 15, lg = lane >> 4;
    const int tM = blockIdx.y * 128, tN = blockIdx.x * 128;

    const int r0 = tid >> 2;
    const int s0 = (tid & 3) * 8;

    f32x4 acc[4][4] = {};

    for (int k0 = 0; k0 < 256; k0 += 32) {
        // --- A stage: bf16 -> bn+relu -> bf16, rows r0 and r0+64 ---
        ushort h0[8], h1[8], d0[8], d1[8];
        *(uint4*)h0 = *(const uint4*)&X1[(size_t)(tM + r0     ) * 256 + k0 + s0];
        *(uint4*)h1 = *(const uint4*)&X1[(size_t)(tM + r0 + 64) * 256 + k0 + s0];
#pragma unroll
        for (int j = 0; j < 8; j++) {
            int c = k0 + s0 + j;
            d0[j] = f2bf(fmaxf(bf2f(h0[j]) * s_sc[c] + s_sh[c], 0.0f));
            d1[j] = f2bf(fmaxf(bf2f(h1[j]) * s_sc[c] + s_sh[c], 0.0f));
        }
        *(uint4*)&As[(r0     ) * 40 + s0] = *(uint4*)d0;
        *(uint4*)&As[(r0 + 64) * 40 + s0] = *(uint4*)d1;

        // --- B stage ---
        *(uint4*)&Bs[(r0     ) * 40 + s0] = *(const uint4*)&W1t[(size_t)(tN + r0     ) * 256 + k0 + s0];
        *(uint4*)&Bs[(r0 + 64) * 40 + s0] = *(const uint4*)&W1t[(size_t)(tN + r0 + 64) * 256 + k0 + s0];
        __syncthreads();

        bfrag af[4], bfv[4];
#pragma unroll
        for (int mm = 0; mm < 4; mm++)
            af[mm] = *(const bfrag*)&As[(wm * 64 + mm * 16 + lr) * 40 + lg * 8];
#pragma unroll
        for (int nn = 0; nn < 4; nn++)
            bfv[nn] = *(const bfrag*)&Bs[(wn * 64 + nn * 16 + lr) * 40 + lg * 8];
#pragma unroll
        for (int mm = 0; mm < 4; mm++)
#pragma unroll
            for (int nn = 0; nn < 4; nn++)
                acc[mm][nn] = __builtin_amdgcn_mfma_f32_16x16x32_bf16(af[mm], bfv[nn], acc[mm][nn], 0, 0, 0);
        __syncthreads();
    }

    if (tN < 256) {
        // Uj half -> YJ table (bias inside, per reference msg = w * (Uj(x)+b))
#pragma unroll
        for (int mm = 0; mm < 4; mm++)
#pragma unroll
            for (int nn = 0; nn < 4; nn++)
#pragma unroll
                for (int r = 0; r < 4; r++) {
                    int row = tM + wm * 64 + mm * 16 + lg * 4 + r;
                    int col = tN + wn * 64 + nn * 16 + lr;
                    YJ[(size_t)row * 256 + col] = f2bf(acc[mm][nn][r] + bias1[col]);
                }
    } else {
        // Ui half + residual -> out base (f32)
#pragma unroll
        for (int mm = 0; mm < 4; mm++) {
#pragma unroll
            for (int r = 0; r < 4; r++) {
                int row = tM + wm * 64 + mm * 16 + lg * 4 + r;
                int c = colof[row];
                float s = valof[row];
#pragma unroll
                for (int nn = 0; nn < 4; nn++) {
                    int col2 = (tN - 256) + wn * 64 + nn * 16 + lr;
                    float v = acc[mm][nn][r] + bias1[256 + col2]
                            + s * bf2f(XW[(size_t)c * 256 + col2]);
                    out[(size_t)row * 256 + col2] = v;
                }
            }
        }
    }
}

// ---------------------------------------------------------------------------
// up UJ table: UJb[r] = bf16(uj0_b + valof[r] * XNU[colof[r], 0:256])
// ---------------------------------------------------------------------------
__global__ __launch_bounds__(256)
void up_uj_kernel(const int* __restrict__ colof, const float* __restrict__ valof,
                  const ushort* __restrict__ XNU, const float* __restrict__ uj_b,
                  ushort* __restrict__ UJb)
{
    int k = blockIdx.x * 4 + (threadIdx.x >> 6);
    int f = (threadIdx.x & 63) * 4;
    int c = colof[k];
    float s = valof[k];
    ushort4 u = *(const ushort4*)&XNU[(size_t)c * 512 + f];
    const ushort* up = (const ushort*)&u;
    ushort o[4];
#pragma unroll
    for (int j = 0; j < 4; j++) o[j] = f2bf(uj_b[f + j] + s * bf2f(up[j]));
    *(ushort4*)&UJb[(size_t)k * 256 + f] = make_ushort4(o[0], o[1], o[2], o[3]);
}

// ---------------------------------------------------------------------------
// Gather layer 0: X1[d] = (ui0_b + valof[d]*XNU[colof[d],256:512]) + sum val*UJb[src]
// one wave per dst row; 2-deep software pipeline on the random row loads
// ---------------------------------------------------------------------------
__global__ __launch_bounds__(256)
void gather0_kernel(const int* __restrict__ offs, const int* __restrict__ cnt,
                    const int* __restrict__ srcs, const float* __restrict__ vals,
                    const int* __restrict__ colof, const float* __restrict__ valof,
                    const ushort* __restrict__ XNU, const float* __restrict__ ui_b,
                    const ushort* __restrict__ UJb, ushort* __restrict__ X1)
{
    int d = blockIdx.x * 4 + (threadIdx.x >> 6);
    int f = (threadIdx.x & 63) * 4;
    int c = colof[d];
    float s = valof[d];
    ushort4 u = *(const ushort4*)&XNU[(size_t)c * 512 + 256 + f];
    const ushort* up = (const ushort*)&u;
    float a0 = ui_b[f + 0] + s * bf2f(up[0]);
    float a1 = ui_b[f + 1] + s * bf2f(up[1]);
    float a2 = ui_b[f + 2] + s * bf2f(up[2]);
    float a3 = ui_b[f + 3] + s * bf2f(up[3]);

    int st = offs[d], n = cnt[d];
    if (n > 0) {
        int   sc = srcs[st];
        float ac = vals[st];
        ushort4 vc = *(const ushort4*)&UJb[(size_t)sc * 256 + f];
        for (int e = 1; e < n; e++) {
            int   sn = srcs[st + e];
            float an = vals[st + e];
            ushort4 vn = *(const ushort4*)&UJb[(size_t)sn * 256 + f];
            const ushort* vp = (const ushort*)&vc;
            a0 += ac * bf2f(vp[0]); a1 += ac * bf2f(vp[1]);
            a2 += ac * bf2f(vp[2]); a3 += ac * bf2f(vp[3]);
            vc = vn; ac = an;
        }
        const ushort* vp = (const ushort*)&vc;
        a0 += ac * bf2f(vp[0]); a1 += ac * bf2f(vp[1]);
        a2 += ac * bf2f(vp[2]); a3 += ac * bf2f(vp[3]);
    }
    *(ushort4*)&X1[(size_t)d * 256 + f] =
        make_ushort4(f2bf(a0), f2bf(a1), f2bf(a2), f2bf(a3));
}

// ---------------------------------------------------------------------------
// Gather layer 1: out[d] += sum val*YJ[src]  (out already holds Ui+residual base)
// ---------------------------------------------------------------------------
__global__ __launch_bounds__(256)
void gather1_kernel(const int* __restrict__ offs, const int* __restrict__ cnt,
                    const int* __restrict__ srcs, const float* __restrict__ vals,
                    const ushort* __restrict__ YJ, float* __restrict__ out)
{
    int d = blockIdx.x * 4 + (threadIdx.x >> 6);
    int f = (threadIdx.x & 63) * 4;
    float4 base = *(const float4*)&out[(size_t)d * 256 + f];
    float a0 = base.x, a1 = base.y, a2 = base.z, a3 = base.w;

    int st = offs[d], n = cnt[d];
    if (n > 0) {
        int   sc = srcs[st];
        float ac = vals[st];
        ushort4 vc = *(const ushort4*)&YJ[(size_t)sc * 256 + f];
        for (int e = 1; e < n; e++) {
            int   sn = srcs[st + e];
            float an = vals[st + e];
            ushort4 vn = *(const ushort4*)&YJ[(size_t)sn * 256 + f];
            const ushort* vp = (const ushort*)&vc;
            a0 += ac * bf2f(vp[0]); a1 += ac * bf2f(vp[1]);
            a2 += ac * bf2f(vp[2]); a3 += ac * bf2f(vp[3]);
            vc = vn; ac = an;
        }
        const ushort* vp = (const ushort*)&vc;
        a0 += ac * bf2f(vp[0]); a1 += ac * bf2f(vp[1]);
        a2 += ac * bf2f(vp[2]); a3 += ac * bf2f(vp[3]);
    }
    *(float4*)&out[(size_t)d * 256 + f] = make_float4(a0, a1, a2, a3);
}

// ---------------------------------------------------------------------------
// Host launcher
// ---------------------------------------------------------------------------
extern "C" void kernel_launch(void* const* d_in, const int* in_sizes, int n_in,
                              void* d_out, int out_size, void* d_ws, size_t ws_size,
                              hipStream_t stream)
{
    const float* x      = (const float*)d_in[0];
    const int*   up_row = (const int*)  d_in[1];
    const int*   up_col = (const int*)  d_in[2];
    const float* up_val = (const float*)d_in[3];
    const int*   e_src  = (const int*)  d_in[4];
    const int*   e_dst  = (const int*)  d_in[5];
    const float* adjv   = (const float*)d_in[6];
    const float* W_res  = (const float*)d_in[7];
    const float* b_res  = (const float*)d_in[8];
    const float* bn0_g  = (const float*)d_in[9];
    const float* bn0_b  = (const float*)d_in[10];
    const float* bn1_g  = (const float*)d_in[11];
    const float* bn1_b  = (const float*)d_in[12];
    const float* Ui0_W  = (const float*)d_in[13];
    const float* Ui0_b  = (const float*)d_in[14];
    const float* Uj0_W  = (const float*)d_in[15];
    const float* Uj0_b  = (const float*)d_in[16];
    const float* Ui1_W  = (const float*)d_in[17];
    const float* Ui1_b  = (const float*)d_in[18];
    const float* Uj1_W  = (const float*)d_in[19];
    const float* Uj1_b  = (const float*)d_in[20];

    float* out = (float*)d_out;

    // ---- workspace layout ----
    char* ws = (char*)d_ws;
    size_t off = 0;
    auto alloc = [&](size_t bytes) -> char* {
        char* p = ws + off;
        off = (off + bytes + 255) & ~(size_t)255;
        return p;
    };
    ushort* XW    = (ushort*)alloc((size_t)V_PREV * F_OUT * 2);   // 8.4 MB
    ushort* XNU   = (ushort*)alloc((size_t)V_PREV * 512 * 2);     // 16.8 MB
    ushort* UJb   = (ushort*)alloc((size_t)V_NEXT * F_OUT * 2);   // 33.6 MB
    ushort* X1    = (ushort*)alloc((size_t)V_NEXT * F_OUT * 2);   // 33.6 MB
    ushort* YJ    = (ushort*)alloc((size_t)V_NEXT * F_OUT * 2);   // 33.6 MB
    int*    cnt   = (int*)   alloc(V_NEXT * 4);
    int*    offs  = (int*)   alloc(V_NEXT * 4);
    int*    cursor= (int*)   alloc(V_NEXT * 4);
    int*    bsum  = (int*)   alloc(256 * 4);
    int*    boff  = (int*)   alloc(256 * 4);
    int*    srcs  = (int*)   alloc((size_t)N_EDGE * 4);
    float*  vals  = (float*) alloc((size_t)N_EDGE * 4);
    int*    colof = (int*)   alloc(V_NEXT * 4);
    float*  valof = (float*) alloc(V_NEXT * 4);
    ushort* WresT = (ushort*)alloc(256 * 512 * 2);
    ushort* W0t   = (ushort*)alloc(512 * 512 * 2);
    ushort* W1t   = (ushort*)alloc(512 * 256 * 2);
    float*  bias1 = (float*) alloc(512 * 4);
    float*  psum0 = (float*) alloc(64 * 512 * 4);
    float*  psq0  = (float*) alloc(64 * 512 * 4);
    float*  sc0   = (float*) alloc(512 * 4);
    float*  sh0   = (float*) alloc(512 * 4);
    float*  psum1 = (float*) alloc(512 * 256 * 4);
    float*  psq1  = (float*) alloc(512 * 256 * 4);
    float*  sc1   = (float*) alloc(256 * 4);
    float*  sh1   = (float*) alloc(256 * 4);
    (void)ws_size; (void)in_sizes; (void)n_in; (void)out_size;

    // ---- weight prep + CSR build (independent of x) ----
    prep_weights_kernel<<<1024, 256, 0, stream>>>(W_res, Ui0_W, Uj0_W, Ui1_W, Uj1_W,
                                                  Ui1_b, Uj1_b, b_res,
                                                  WresT, W0t, W1t, bias1);
    hipMemsetAsync(cnt, 0, (size_t)V_NEXT * 4, stream);
    hist_kernel<<<N_EDGE / 256, 256, 0, stream>>>(e_dst, cnt);
    scan_block_kernel<<<256, 256, 0, stream>>>(cnt, offs, bsum);
    scan_top_kernel<<<1, 256, 0, stream>>>(bsum, boff);
    add_offs_kernel<<<256, 256, 0, stream>>>(offs, boff, cursor);
    fill_kernel<<<N_EDGE / 256, 256, 0, stream>>>(e_src, e_dst, adjv, cursor, srcs, vals);
    invert_up_kernel<<<NNZ_UP / 256, 256, 0, stream>>>(up_row, up_col, up_val, colof, valof);

    // ---- bn0 stats ----
    bn0_part_kernel<<<64, 256, 0, stream>>>(x, psum0, psq0);
    bn_finish_kernel<<<2, 256, 0, stream>>>(psum0, psq0, 64, 512, 1.0f / V_PREV,
                                            bn0_g, bn0_b, sc0, sh0);

    // ---- GEMM0 (fused bn0+relu+cast): XW [16384,256], XNU [16384,512] ----
    gemm0_fused_kernel<<<dim3(6, 128), 256, 0, stream>>>(x, WresT, W0t, sc0, sh0, XW, XNU);

    // ---- UJ table (upsample of Uj0 part) ----
    up_uj_kernel<<<NNZ_UP / 4, 256, 0, stream>>>(colof, valof, XNU, Uj0_b, UJb);

    // ---- ECC layer 0 aggregation ----
    gather0_kernel<<<V_NEXT / 4, 256, 0, stream>>>(offs, cnt, srcs, vals,
                                                   colof, valof, XNU, Ui0_b, UJb, X1);

    // ---- bn1 stats ----
    bn1_part_bf16_kernel<<<512, 256, 0, stream>>>(X1, psum1, psq1);
    bn_finish_kernel<<<1, 256, 0, stream>>>(psum1, psq1, 512, 256, 1.0f / V_NEXT,
                                            bn1_g, bn1_b, sc1, sh1);

    // ---- GEMM1 (fused bn1+relu; epilogue residual): YJ + out base ----
    gemm1_fused_kernel<<<dim3(4, 512), 256, 0, stream>>>(X1, W1t, sc1, sh1, bias1,
                                                         colof, valof, XW, YJ, out);

    // ---- ECC layer 1 aggregation into out ----
    gather1_kernel<<<V_NEXT / 4, 256, 0, stream>>>(offs, cnt, srcs, vals, YJ, out);
}

// Round 4
// 317.520 us; speedup vs baseline: 13.8577x; 1.4895x over previous
//
#include <hip/hip_runtime.h>

// ---------------------------------------------------------------------------
// Problem constants
// ---------------------------------------------------------------------------
#define V_PREV 16384
#define V_NEXT 65536
#define F_IN   512
#define F_OUT  256
#define NNZ_UP 65536
#define N_EDGE 524288

using f32x4 = __attribute__((ext_vector_type(4))) float;
using bfrag = __attribute__((ext_vector_type(8))) short;   // 8 x bf16

__device__ __forceinline__ ushort f2bf(float f) {
    union { float f; unsigned u; } v; v.f = f;
    unsigned r = (v.u + 0x7FFFu + ((v.u >> 16) & 1u)) >> 16;
    return (ushort)r;
}
__device__ __forceinline__ float bf2f(ushort h) {
    union { unsigned u; float f; } v; v.u = ((unsigned)h) << 16; return v.f;
}

// ---------------------------------------------------------------------------
// Weight prep (transpose + bf16, concat Uj|Ui; bias1 Ui-half folds b_res)
// ---------------------------------------------------------------------------
__global__ void prep_weights_kernel(const float* __restrict__ Wres,
                                    const float* __restrict__ Ui0W, const float* __restrict__ Uj0W,
                                    const float* __restrict__ Ui1W, const float* __restrict__ Uj1W,
                                    const float* __restrict__ Ui1b, const float* __restrict__ Uj1b,
                                    const float* __restrict__ bres,
                                    ushort* __restrict__ WresT, ushort* __restrict__ W0t,
                                    ushort* __restrict__ W1t, float* __restrict__ bias1)
{
    int i = blockIdx.x * blockDim.x + threadIdx.x;   // 0 .. 512*512-1
    if (i < 256 * 512) {
        int n = i / 512, k = i % 512;
        WresT[i] = f2bf(Wres[k * 256 + n]);
    }
    if (i < 512 * 512) {
        int n = i / 512, k = i % 512;
        W0t[i] = f2bf(n < 256 ? Uj0W[k * 256 + n] : Ui0W[k * 256 + (n - 256)]);
    }
    if (i < 512 * 256) {
        int n = i / 256, k = i % 256;
        W1t[i] = f2bf(n < 256 ? Uj1W[k * 256 + n] : Ui1W[k * 256 + (n - 256)]);
    }
    if (i < 512) bias1[i] = (i < 256) ? Uj1b[i] : (Ui1b[i - 256] + bres[i - 256]);
}

// ---------------------------------------------------------------------------
// CSR build: histogram -> 2-level exclusive scan -> fill (dst-sorted src/val)
// ---------------------------------------------------------------------------
__global__ void hist_kernel(const int* __restrict__ dst, int* __restrict__ cnt) {
    int e = blockIdx.x * blockDim.x + threadIdx.x;
    atomicAdd(&cnt[dst[e]], 1);
}

__global__ void scan_block_kernel(const int* __restrict__ cnt, int* __restrict__ offs,
                                  int* __restrict__ bsum)
{
    __shared__ int buf[2][256];
    int t = threadIdx.x;
    int i = blockIdx.x * 256 + t;
    int v = cnt[i];
    int p = 0;
    buf[0][t] = v;
    __syncthreads();
    for (int d = 1; d < 256; d <<= 1) {
        int nv = buf[p][t] + ((t >= d) ? buf[p][t - d] : 0);
        buf[p ^ 1][t] = nv;
        p ^= 1;
        __syncthreads();
    }
    int incl = buf[p][t];
    offs[i] = incl - v;
    if (t == 255) bsum[blockIdx.x] = incl;
}

__global__ void scan_top_kernel(const int* __restrict__ bsum, int* __restrict__ boff)
{
    __shared__ int buf[2][256];
    int t = threadIdx.x;
    int v = bsum[t];
    int p = 0;
    buf[0][t] = v;
    __syncthreads();
    for (int d = 1; d < 256; d <<= 1) {
        int nv = buf[p][t] + ((t >= d) ? buf[p][t - d] : 0);
        buf[p ^ 1][t] = nv;
        p ^= 1;
        __syncthreads();
    }
    boff[t] = buf[p][t] - v;
}

__global__ void add_offs_kernel(int* __restrict__ offs, const int* __restrict__ boff,
                                int* __restrict__ cursor)
{
    int i = blockIdx.x * 256 + threadIdx.x;
    int o = offs[i] + boff[blockIdx.x];
    offs[i] = o;
    cursor[i] = o;
}

__global__ void fill_kernel(const int* __restrict__ src, const int* __restrict__ dst,
                            const float* __restrict__ adjv,
                            int* __restrict__ cursor, int* __restrict__ srcs,
                            float* __restrict__ vals)
{
    int e = blockIdx.x * blockDim.x + threadIdx.x;
    int d = dst[e];
    int p = atomicAdd(&cursor[d], 1);
    srcs[p] = src[e];
    vals[p] = adjv[e];
}

// Invert the up map: colof[up_row[k]] = up_col[k], valof[up_row[k]] = up_val[k]
__global__ void invert_up_kernel(const int* __restrict__ up_row, const int* __restrict__ up_col,
                                 const float* __restrict__ up_val,
                                 int* __restrict__ colof, float* __restrict__ valof)
{
    int k = blockIdx.x * blockDim.x + threadIdx.x;
    int r = up_row[k];
    colof[r] = up_col[k];
    valof[r] = up_val[k];
}

// ---------------------------------------------------------------------------
// BatchNorm stats
// ---------------------------------------------------------------------------
// 128 blocks x 128 rows; thread handles ch t and t+256
__global__ void bn0_part_kernel(const float* __restrict__ x,
                                float* __restrict__ psum, float* __restrict__ psq)
{
    int blk = blockIdx.x, t = threadIdx.x;
    float s0 = 0, s1 = 0, q0 = 0, q1 = 0;
    for (int r = 0; r < 128; r++) {
        size_t base = ((size_t)blk * 128 + r) * 512;
        float a = x[base + t], b = x[base + t + 256];
        s0 += a; q0 += a * a; s1 += b; q1 += b * b;
    }
    psum[blk * 512 + t] = s0; psum[blk * 512 + t + 256] = s1;
    psq [blk * 512 + t] = q0; psq [blk * 512 + t + 256] = q1;
}

// X1 bf16 [65536,256]; 512 blocks x 128 rows
__global__ void bn1_part_bf16_kernel(const ushort* __restrict__ xx,
                                     float* __restrict__ psum, float* __restrict__ psq)
{
    int blk = blockIdx.x, t = threadIdx.x;
    float s = 0, q = 0;
    for (int r = 0; r < 128; r++) {
        float a = bf2f(xx[((size_t)blk * 128 + r) * 256 + t]);
        s += a; q += a * a;
    }
    psum[blk * 256 + t] = s; psq[blk * 256 + t] = q;
}

// Parallel finish: one wave per channel; lane l sums partial rows l, l+64, ...
// then butterfly-reduce. Produces affine: sc = g*rstd, sh = b - mean*sc.
__global__ void bn_finish_kernel(const float* __restrict__ psum, const float* __restrict__ psq,
                                 int nblocks, int C, float invN,
                                 const float* __restrict__ g, const float* __restrict__ b,
                                 float* __restrict__ sc, float* __restrict__ sh)
{
    int gw = (blockIdx.x * blockDim.x + threadIdx.x) >> 6;   // global wave id = channel
    int lane = threadIdx.x & 63;
    if (gw >= C) return;
    float s = 0, q = 0;
    for (int i = lane; i < nblocks; i += 64) {
        s += psum[(size_t)i * C + gw];
        q += psq [(size_t)i * C + gw];
    }
#pragma unroll
    for (int d = 32; d > 0; d >>= 1) {
        s += __shfl_xor(s, d);
        q += __shfl_xor(q, d);
    }
    if (lane == 0) {
        float m = s * invN;
        float v = q * invN - m * m;
        float r = rsqrtf(v + 1e-5f);
        float scale = r * g[gw];
        sc[gw] = scale;
        sh[gw] = b[gw] - m * scale;
    }
}

// ---------------------------------------------------------------------------
// GEMM0 fused: reads x f32 [16384,512] directly.
//   blocks bx<2:  XW  = bf16(x) @ WresT^T          (raw A)
//   blocks bx>=2: XNU = bf16(relu(bn0(x))) @ W0t^T (bn A)
// 128x128 tile, BK=32, 4 waves (2x2), mfma 16x16x32.
// ---------------------------------------------------------------------------
__global__ __launch_bounds__(256)
void gemm0_fused_kernel(const float* __restrict__ x,
                        const ushort* __restrict__ WresT, const ushort* __restrict__ W0t,
                        const float* __restrict__ sc0, const float* __restrict__ sh0,
                        ushort* __restrict__ XW, ushort* __restrict__ XNU)
{
    __shared__ ushort As[128 * 40];
    __shared__ ushort Bs[128 * 40];
    __shared__ float s_sc[512], s_sh[512];

    const int tid = threadIdx.x;
    const bool bnmode = blockIdx.x >= 2;
    const ushort* Bt = bnmode ? W0t : WresT;
    const int tN  = blockIdx.x * 128;
    const int tNl = bnmode ? tN - 256 : tN;
    const int Nout = bnmode ? 512 : 256;
    ushort* Cout = bnmode ? XNU : XW;
    const int tM = blockIdx.y * 128;

    for (int i = tid; i < 512; i += 256) { s_sc[i] = sc0[i]; s_sh[i] = sh0[i]; }
    __syncthreads();

    const int lane = tid & 63;
    const int wave = tid >> 6;
    const int wm = wave >> 1, wn = wave & 1;
    const int lr = lane & 15, lg = lane >> 4;

    const int ra = tid >> 1;            // A-stage row 0..127
    const int sa = (tid & 1) * 16;      // A-stage col 0 or 16
    const int rb = tid >> 2;            // B-stage row 0..63
    const int sb = (tid & 3) * 8;       // B-stage col 0,8,16,24

    f32x4 acc[4][4] = {};

    for (int k0 = 0; k0 < 512; k0 += 32) {
        // --- A stage: 16 f32 -> bf16 (optional bn+relu) ---
        const float* xp = &x[(size_t)(tM + ra) * 512 + k0 + sa];
        float4 f0 = *(const float4*)(xp);
        float4 f1 = *(const float4*)(xp + 4);
        float4 f2 = *(const float4*)(xp + 8);
        float4 f3 = *(const float4*)(xp + 12);
        float vv[16] = { f0.x,f0.y,f0.z,f0.w, f1.x,f1.y,f1.z,f1.w,
                         f2.x,f2.y,f2.z,f2.w, f3.x,f3.y,f3.z,f3.w };
        ushort hh[16];
        if (bnmode) {
#pragma unroll
            for (int j = 0; j < 16; j++) {
                int c = k0 + sa + j;
                hh[j] = f2bf(fmaxf(vv[j] * s_sc[c] + s_sh[c], 0.0f));
            }
        } else {
#pragma unroll
            for (int j = 0; j < 16; j++) hh[j] = f2bf(vv[j]);
        }
        *(uint4*)&As[ra * 40 + sa]     = *(uint4*)&hh[0];
        *(uint4*)&As[ra * 40 + sa + 8] = *(uint4*)&hh[8];

        // --- B stage ---
        *(uint4*)&Bs[(rb     ) * 40 + sb] = *(const uint4*)&Bt[(size_t)(tNl + rb     ) * 512 + k0 + sb];
        *(uint4*)&Bs[(rb + 64) * 40 + sb] = *(const uint4*)&Bt[(size_t)(tNl + rb + 64) * 512 + k0 + sb];
        __syncthreads();

        bfrag af[4], bfv[4];
#pragma unroll
        for (int mm = 0; mm < 4; mm++)
            af[mm] = *(const bfrag*)&As[(wm * 64 + mm * 16 + lr) * 40 + lg * 8];
#pragma unroll
        for (int nn = 0; nn < 4; nn++)
            bfv[nn] = *(const bfrag*)&Bs[(wn * 64 + nn * 16 + lr) * 40 + lg * 8];
#pragma unroll
        for (int mm = 0; mm < 4; mm++)
#pragma unroll
            for (int nn = 0; nn < 4; nn++)
                acc[mm][nn] = __builtin_amdgcn_mfma_f32_16x16x32_bf16(af[mm], bfv[nn], acc[mm][nn], 0, 0, 0);
        __syncthreads();
    }

#pragma unroll
    for (int mm = 0; mm < 4; mm++)
#pragma unroll
        for (int nn = 0; nn < 4; nn++)
#pragma unroll
            for (int r = 0; r < 4; r++) {
                int row = tM + wm * 64 + mm * 16 + lg * 4 + r;
                int col = tNl + wn * 64 + nn * 16 + lr;
                Cout[(size_t)row * Nout + col] = f2bf(acc[mm][nn][r]);
            }
}

// ---------------------------------------------------------------------------
// GEMM1 fused: A = relu(bn1(X1)) applied in staging; Bt = W1t [512][256].
//   bx<2 : YJ  (bf16) = A @ Uj1 + Uj1_b                (the gathered table)
//   bx>=2: out (f32)  = A @ Ui1 + (Ui1_b + b_res) + up_val*XW[up_col] (residual)
// ---------------------------------------------------------------------------
__global__ __launch_bounds__(256)
void gemm1_fused_kernel(const ushort* __restrict__ X1, const ushort* __restrict__ W1t,
                        const float* __restrict__ sc1, const float* __restrict__ sh1,
                        const float* __restrict__ bias1,
                        const int* __restrict__ colof, const float* __restrict__ valof,
                        const ushort* __restrict__ XW,
                        ushort* __restrict__ YJ, float* __restrict__ out)
{
    __shared__ ushort As[128 * 40];
    __shared__ ushort Bs[128 * 40];
    __shared__ float s_sc[256], s_sh[256];

    const int tid = threadIdx.x;
    for (int i = tid; i < 256; i += 256) { s_sc[i] = sc1[i]; s_sh[i] = sh1[i]; }
    __syncthreads();

    const int lane = tid & 63;
    const int wave = tid >> 6;
    const int wm = wave >> 1, wn = wave & 1;
    const int lr = lane & 15, lg = lane >> 4;
    const int tM = blockIdx.y * 128, tN = blockIdx.x * 128;

    const int r0 = tid >> 2;
    const int s0 = (tid & 3) * 8;

    f32x4 acc[4][4] = {};

    for (int k0 = 0; k0 < 256; k0 += 32) {
        // --- A stage: bf16 -> bn+relu -> bf16, rows r0 and r0+64 ---
        ushort h0[8], h1[8], d0[8], d1[8];
        *(uint4*)h0 = *(const uint4*)&X1[(size_t)(tM + r0     ) * 256 + k0 + s0];
        *(uint4*)h1 = *(const uint4*)&X1[(size_t)(tM + r0 + 64) * 256 + k0 + s0];
#pragma unroll
        for (int j = 0; j < 8; j++) {
            int c = k0 + s0 + j;
            d0[j] = f2bf(fmaxf(bf2f(h0[j]) * s_sc[c] + s_sh[c], 0.0f));
            d1[j] = f2bf(fmaxf(bf2f(h1[j]) * s_sc[c] + s_sh[c], 0.0f));
        }
        *(uint4*)&As[(r0     ) * 40 + s0] = *(uint4*)d0;
        *(uint4*)&As[(r0 + 64) * 40 + s0] = *(uint4*)d1;

        // --- B stage ---
        *(uint4*)&Bs[(r0     ) * 40 + s0] = *(const uint4*)&W1t[(size_t)(tN + r0     ) * 256 + k0 + s0];
        *(uint4*)&Bs[(r0 + 64) * 40 + s0] = *(const uint4*)&W1t[(size_t)(tN + r0 + 64) * 256 + k0 + s0];
        __syncthreads();

        bfrag af[4], bfv[4];
#pragma unroll
        for (int mm = 0; mm < 4; mm++)
            af[mm] = *(const bfrag*)&As[(wm * 64 + mm * 16 + lr) * 40 + lg * 8];
#pragma unroll
        for (int nn = 0; nn < 4; nn++)
            bfv[nn] = *(const bfrag*)&Bs[(wn * 64 + nn * 16 + lr) * 40 + lg * 8];
#pragma unroll
        for (int mm = 0; mm < 4; mm++)
#pragma unroll
            for (int nn = 0; nn < 4; nn++)
                acc[mm][nn] = __builtin_amdgcn_mfma_f32_16x16x32_bf16(af[mm], bfv[nn], acc[mm][nn], 0, 0, 0);
        __syncthreads();
    }

    if (tN < 256) {
        // Uj half -> YJ table (bias inside, per reference msg = w * (Uj(x)+b))
#pragma unroll
        for (int mm = 0; mm < 4; mm++)
#pragma unroll
            for (int nn = 0; nn < 4; nn++)
#pragma unroll
                for (int r = 0; r < 4; r++) {
                    int row = tM + wm * 64 + mm * 16 + lg * 4 + r;
                    int col = tN + wn * 64 + nn * 16 + lr;
                    YJ[(size_t)row * 256 + col] = f2bf(acc[mm][nn][r] + bias1[col]);
                }
    } else {
        // Ui half + residual -> out base (f32)
#pragma unroll
        for (int mm = 0; mm < 4; mm++) {
#pragma unroll
            for (int r = 0; r < 4; r++) {
                int row = tM + wm * 64 + mm * 16 + lg * 4 + r;
                int c = colof[row];
                float s = valof[row];
#pragma unroll
                for (int nn = 0; nn < 4; nn++) {
                    int col2 = (tN - 256) + wn * 64 + nn * 16 + lr;
                    float v = acc[mm][nn][r] + bias1[256 + col2]
                            + s * bf2f(XW[(size_t)c * 256 + col2]);
                    out[(size_t)row * 256 + col2] = v;
                }
            }
        }
    }
}

// ---------------------------------------------------------------------------
// up UJ table: UJb[r] = bf16(uj0_b + valof[r] * XNU[colof[r], 0:256])
// ---------------------------------------------------------------------------
__global__ __launch_bounds__(256)
void up_uj_kernel(const int* __restrict__ colof, const float* __restrict__ valof,
                  const ushort* __restrict__ XNU, const float* __restrict__ uj_b,
                  ushort* __restrict__ UJb)
{
    int k = blockIdx.x * 4 + (threadIdx.x >> 6);
    int f = (threadIdx.x & 63) * 4;
    int c = colof[k];
    float s = valof[k];
    ushort4 u = *(const ushort4*)&XNU[(size_t)c * 512 + f];
    const ushort* up = (const ushort*)&u;
    ushort o[4];
#pragma unroll
    for (int j = 0; j < 4; j++) o[j] = f2bf(uj_b[f + j] + s * bf2f(up[j]));
    *(ushort4*)&UJb[(size_t)k * 256 + f] = make_ushort4(o[0], o[1], o[2], o[3]);
}

// ---------------------------------------------------------------------------
// Gather layer 0: X1[d] = (ui0_b + valof[d]*XNU[colof[d],256:512]) + sum val*UJb[src]
// ---------------------------------------------------------------------------
__global__ __launch_bounds__(256)
void gather0_kernel(const int* __restrict__ offs, const int* __restrict__ cnt,
                    const int* __restrict__ srcs, const float* __restrict__ vals,
                    const int* __restrict__ colof, const float* __restrict__ valof,
                    const ushort* __restrict__ XNU, const float* __restrict__ ui_b,
                    const ushort* __restrict__ UJb, ushort* __restrict__ X1)
{
    int d = blockIdx.x * 4 + (threadIdx.x >> 6);
    int f = (threadIdx.x & 63) * 4;
    int c = colof[d];
    float s = valof[d];
    ushort4 u = *(const ushort4*)&XNU[(size_t)c * 512 + 256 + f];
    const ushort* up = (const ushort*)&u;
    float a0 = ui_b[f + 0] + s * bf2f(up[0]);
    float a1 = ui_b[f + 1] + s * bf2f(up[1]);
    float a2 = ui_b[f + 2] + s * bf2f(up[2]);
    float a3 = ui_b[f + 3] + s * bf2f(up[3]);

    int st = offs[d], n = cnt[d];
    if (n > 0) {
        int   sc = srcs[st];
        float ac = vals[st];
        ushort4 vc = *(const ushort4*)&UJb[(size_t)sc * 256 + f];
        for (int e = 1; e < n; e++) {
            int   sn = srcs[st + e];
            float an = vals[st + e];
            ushort4 vn = *(const ushort4*)&UJb[(size_t)sn * 256 + f];
            const ushort* vp = (const ushort*)&vc;
            a0 += ac * bf2f(vp[0]); a1 += ac * bf2f(vp[1]);
            a2 += ac * bf2f(vp[2]); a3 += ac * bf2f(vp[3]);
            vc = vn; ac = an;
        }
        const ushort* vp = (const ushort*)&vc;
        a0 += ac * bf2f(vp[0]); a1 += ac * bf2f(vp[1]);
        a2 += ac * bf2f(vp[2]); a3 += ac * bf2f(vp[3]);
    }
    *(ushort4*)&X1[(size_t)d * 256 + f] =
        make_ushort4(f2bf(a0), f2bf(a1), f2bf(a2), f2bf(a3));
}

// ---------------------------------------------------------------------------
// Gather layer 1: out[d] += sum val*YJ[src]  (out already holds Ui+residual base)
// ---------------------------------------------------------------------------
__global__ __launch_bounds__(256)
void gather1_kernel(const int* __restrict__ offs, const int* __restrict__ cnt,
                    const int* __restrict__ srcs, const float* __restrict__ vals,
                    const ushort* __restrict__ YJ, float* __restrict__ out)
{
    int d = blockIdx.x * 4 + (threadIdx.x >> 6);
    int f = (threadIdx.x & 63) * 4;
    float4 base = *(const float4*)&out[(size_t)d * 256 + f];
    float a0 = base.x, a1 = base.y, a2 = base.z, a3 = base.w;

    int st = offs[d], n = cnt[d];
    if (n > 0) {
        int   sc = srcs[st];
        float ac = vals[st];
        ushort4 vc = *(const ushort4*)&YJ[(size_t)sc * 256 + f];
        for (int e = 1; e < n; e++) {
            int   sn = srcs[st + e];
            float an = vals[st + e];
            ushort4 vn = *(const ushort4*)&YJ[(size_t)sn * 256 + f];
            const ushort* vp = (const ushort*)&vc;
            a0 += ac * bf2f(vp[0]); a1 += ac * bf2f(vp[1]);
            a2 += ac * bf2f(vp[2]); a3 += ac * bf2f(vp[3]);
            vc = vn; ac = an;
        }
        const ushort* vp = (const ushort*)&vc;
        a0 += ac * bf2f(vp[0]); a1 += ac * bf2f(vp[1]);
        a2 += ac * bf2f(vp[2]); a3 += ac * bf2f(vp[3]);
    }
    *(float4*)&out[(size_t)d * 256 + f] = make_float4(a0, a1, a2, a3);
}

// ---------------------------------------------------------------------------
// Host launcher
// ---------------------------------------------------------------------------
extern "C" void kernel_launch(void* const* d_in, const int* in_sizes, int n_in,
                              void* d_out, int out_size, void* d_ws, size_t ws_size,
                              hipStream_t stream)
{
    const float* x      = (const float*)d_in[0];
    const int*   up_row = (const int*)  d_in[1];
    const int*   up_col = (const int*)  d_in[2];
    const float* up_val = (const float*)d_in[3];
    const int*   e_src  = (const int*)  d_in[4];
    const int*   e_dst  = (const int*)  d_in[5];
    const float* adjv   = (const float*)d_in[6];
    const float* W_res  = (const float*)d_in[7];
    const float* b_res  = (const float*)d_in[8];
    const float* bn0_g  = (const float*)d_in[9];
    const float* bn0_b  = (const float*)d_in[10];
    const float* bn1_g  = (const float*)d_in[11];
    const float* bn1_b  = (const float*)d_in[12];
    const float* Ui0_W  = (const float*)d_in[13];
    const float* Ui0_b  = (const float*)d_in[14];
    const float* Uj0_W  = (const float*)d_in[15];
    const float* Uj0_b  = (const float*)d_in[16];
    const float* Ui1_W  = (const float*)d_in[17];
    const float* Ui1_b  = (const float*)d_in[18];
    const float* Uj1_W  = (const float*)d_in[19];
    const float* Uj1_b  = (const float*)d_in[20];

    float* out = (float*)d_out;

    // ---- workspace layout ----
    char* ws = (char*)d_ws;
    size_t off = 0;
    auto alloc = [&](size_t bytes) -> char* {
        char* p = ws + off;
        off = (off + bytes + 255) & ~(size_t)255;
        return p;
    };
    ushort* XW    = (ushort*)alloc((size_t)V_PREV * F_OUT * 2);   // 8.4 MB
    ushort* XNU   = (ushort*)alloc((size_t)V_PREV * 512 * 2);     // 16.8 MB
    ushort* UJb   = (ushort*)alloc((size_t)V_NEXT * F_OUT * 2);   // 33.6 MB
    ushort* X1    = (ushort*)alloc((size_t)V_NEXT * F_OUT * 2);   // 33.6 MB
    ushort* YJ    = (ushort*)alloc((size_t)V_NEXT * F_OUT * 2);   // 33.6 MB
    int*    cnt   = (int*)   alloc(V_NEXT * 4);
    int*    offs  = (int*)   alloc(V_NEXT * 4);
    int*    cursor= (int*)   alloc(V_NEXT * 4);
    int*    bsum  = (int*)   alloc(256 * 4);
    int*    boff  = (int*)   alloc(256 * 4);
    int*    srcs  = (int*)   alloc((size_t)N_EDGE * 4);
    float*  vals  = (float*) alloc((size_t)N_EDGE * 4);
    int*    colof = (int*)   alloc(V_NEXT * 4);
    float*  valof = (float*) alloc(V_NEXT * 4);
    ushort* WresT = (ushort*)alloc(256 * 512 * 2);
    ushort* W0t   = (ushort*)alloc(512 * 512 * 2);
    ushort* W1t   = (ushort*)alloc(512 * 256 * 2);
    float*  bias1 = (float*) alloc(512 * 4);
    float*  psum0 = (float*) alloc(128 * 512 * 4);
    float*  psq0  = (float*) alloc(128 * 512 * 4);
    float*  sc0   = (float*) alloc(512 * 4);
    float*  sh0   = (float*) alloc(512 * 4);
    float*  psum1 = (float*) alloc(512 * 256 * 4);
    float*  psq1  = (float*) alloc(512 * 256 * 4);
    float*  sc1   = (float*) alloc(256 * 4);
    float*  sh1   = (float*) alloc(256 * 4);
    (void)ws_size; (void)in_sizes; (void)n_in; (void)out_size;

    // ---- weight prep + CSR build (independent of x) ----
    prep_weights_kernel<<<1024, 256, 0, stream>>>(W_res, Ui0_W, Uj0_W, Ui1_W, Uj1_W,
                                                  Ui1_b, Uj1_b, b_res,
                                                  WresT, W0t, W1t, bias1);
    hipMemsetAsync(cnt, 0, (size_t)V_NEXT * 4, stream);
    hist_kernel<<<N_EDGE / 256, 256, 0, stream>>>(e_dst, cnt);
    scan_block_kernel<<<256, 256, 0, stream>>>(cnt, offs, bsum);
    scan_top_kernel<<<1, 256, 0, stream>>>(bsum, boff);
    add_offs_kernel<<<256, 256, 0, stream>>>(offs, boff, cursor);
    fill_kernel<<<N_EDGE / 256, 256, 0, stream>>>(e_src, e_dst, adjv, cursor, srcs, vals);
    invert_up_kernel<<<NNZ_UP / 256, 256, 0, stream>>>(up_row, up_col, up_val, colof, valof);

    // ---- bn0 stats ----
    bn0_part_kernel<<<128, 256, 0, stream>>>(x, psum0, psq0);
    bn_finish_kernel<<<128, 256, 0, stream>>>(psum0, psq0, 128, 512, 1.0f / V_PREV,
                                              bn0_g, bn0_b, sc0, sh0);

    // ---- GEMM0 (fused bn0+relu+cast): XW [16384,256], XNU [16384,512] ----
    gemm0_fused_kernel<<<dim3(6, 128), 256, 0, stream>>>(x, WresT, W0t, sc0, sh0, XW, XNU);

    // ---- UJ table (upsample of Uj0 part) ----
    up_uj_kernel<<<NNZ_UP / 4, 256, 0, stream>>>(colof, valof, XNU, Uj0_b, UJb);

    // ---- ECC layer 0 aggregation ----
    gather0_kernel<<<V_NEXT / 4, 256, 0, stream>>>(offs, cnt, srcs, vals,
                                                   colof, valof, XNU, Ui0_b, UJb, X1);

    // ---- bn1 stats ----
    bn1_part_bf16_kernel<<<512, 256, 0, stream>>>(X1, psum1, psq1);
    bn_finish_kernel<<<64, 256, 0, stream>>>(psum1, psq1, 512, 256, 1.0f / V_NEXT,
                                             bn1_g, bn1_b, sc1, sh1);

    // ---- GEMM1 (fused bn1+relu; epilogue residual): YJ + out base ----
    gemm1_fused_kernel<<<dim3(4, 512), 256, 0, stream>>>(X1, W1t, sc1, sh1, bias1,
                                                         colof, valof, XW, YJ, out);

    // ---- ECC layer 1 aggregation into out ----
    gather1_kernel<<<V_NEXT / 4, 256, 0, stream>>>(offs, cnt, srcs, vals, YJ, out);
}